// Round 16
// baseline (112.587 us; speedup 1.0000x reference)
//
#include <hip/hip_runtime.h>
#include <math.h>

// Problem constants (match reference)
#define FIN   128
#define HC1   128   // H*C for layer 1
#define NCLS  16
#define NEG_SLOPE 0.2f

typedef __attribute__((ext_vector_type(8))) short bf16x8;
typedef __attribute__((ext_vector_type(4))) float f32x4;

__device__ __forceinline__ unsigned short f2bf_rne(float f) {
    unsigned int u = __float_as_uint(f);
    unsigned int r = u + 0x7FFFu + ((u >> 16) & 1u);
    return (unsigned short)(r >> 16);
}
__device__ __forceinline__ float bf2f(unsigned short h) {
    return __uint_as_float(((unsigned int)h) << 16);
}
__device__ __forceinline__ float bflo(unsigned int u) { return __uint_as_float(u << 16); }
__device__ __forceinline__ float bfhi(unsigned int u) { return __uint_as_float(u & 0xFFFF0000u); }

__device__ __forceinline__ void acc8(float (&acc)[8], uint4 u, float w) {
    acc[0] = fmaf(bflo(u.x), w, acc[0]);
    acc[1] = fmaf(bfhi(u.x), w, acc[1]);
    acc[2] = fmaf(bflo(u.y), w, acc[2]);
    acc[3] = fmaf(bfhi(u.y), w, acc[3]);
    acc[4] = fmaf(bflo(u.z), w, acc[4]);
    acc[5] = fmaf(bfhi(u.z), w, acc[5]);
    acc[6] = fmaf(bflo(u.w), w, acc[6]);
    acc[7] = fmaf(bfhi(u.w), w, acc[7]);
}

#define EPB 4096   // edges per block in bcnt/binA  (EB = ceil(E/EPB) must be <=256)

// ---------------------------------------------------------------------------
// gemm1 body (split-bf16 MFMA, h1=x@W1 -> bf16, fused alpha1 reductions).
// ---------------------------------------------------------------------------
__device__ __forceinline__
void gemm1_body(const float* __restrict__ x, const float* __restrict__ W,
                const float* __restrict__ a_src, const float* __restrict__ a_dst,
                unsigned short* __restrict__ h1b, float* __restrict__ as1,
                float* __restrict__ ad1, int N, int bid, float4* smem) {
    unsigned short* whi = (unsigned short*)smem;          // 32 KB
    unsigned short* wlo = whi + FIN * HC1;                // 32 KB
    int tid = threadIdx.x;

#pragma unroll
    for (int i = 0; i < 64; ++i) {
        int idx = tid + i * 256;            // 0..16383, coalesced
        int k = idx >> 7, c = idx & 127;
        float v = W[idx];
        unsigned short hb = f2bf_rne(v);
        unsigned short lb = f2bf_rne(v - bf2f(hb));
        int kb = k >> 5, kk = k & 31;
        int g = kk >> 3, j = kk & 7;
        int ct = c >> 4, li = c & 15;
        int off = ((kb * 8 + ct) * 64 + g * 16 + li) * 8 + j;
        whi[off] = hb;
        wlo[off] = lb;
    }

    int wid = tid >> 6, lane = tid & 63;
    int li = lane & 15, g = lane >> 4;
    int rowbase = bid * 64 + wid * 16;

    int arow = rowbase + li;
    if (arow >= N) arow = N - 1;            // clamp; invalid rows never stored
    const float* xp = x + (long)arow * FIN + g * 8;
    bf16x8 Ahi[4], Alo[4];
#pragma unroll
    for (int kb = 0; kb < 4; ++kb) {
        float4 v0 = *reinterpret_cast<const float4*>(xp + kb * 32);
        float4 v1 = *reinterpret_cast<const float4*>(xp + kb * 32 + 4);
        float vs0 = v0.x, vs1 = v0.y, vs2 = v0.z, vs3 = v0.w;
        float vs4 = v1.x, vs5 = v1.y, vs6 = v1.z, vs7 = v1.w;
        bf16x8 h8, l8;
        unsigned short hb;
        hb = f2bf_rne(vs0); h8[0] = (short)hb; l8[0] = (short)f2bf_rne(vs0 - bf2f(hb));
        hb = f2bf_rne(vs1); h8[1] = (short)hb; l8[1] = (short)f2bf_rne(vs1 - bf2f(hb));
        hb = f2bf_rne(vs2); h8[2] = (short)hb; l8[2] = (short)f2bf_rne(vs2 - bf2f(hb));
        hb = f2bf_rne(vs3); h8[3] = (short)hb; l8[3] = (short)f2bf_rne(vs3 - bf2f(hb));
        hb = f2bf_rne(vs4); h8[4] = (short)hb; l8[4] = (short)f2bf_rne(vs4 - bf2f(hb));
        hb = f2bf_rne(vs5); h8[5] = (short)hb; l8[5] = (short)f2bf_rne(vs5 - bf2f(hb));
        hb = f2bf_rne(vs6); h8[6] = (short)hb; l8[6] = (short)f2bf_rne(vs6 - bf2f(hb));
        hb = f2bf_rne(vs7); h8[7] = (short)hb; l8[7] = (short)f2bf_rne(vs7 - bf2f(hb));
        Ahi[kb] = h8; Alo[kb] = l8;
    }

    float asr[8], adr[8];
#pragma unroll
    for (int ct = 0; ct < 8; ++ct) {
        asr[ct] = a_src[ct * 16 + li];
        adr[ct] = a_dst[ct * 16 + li];
    }

    __syncthreads();

    f32x4 acc[8];
#pragma unroll
    for (int ct = 0; ct < 8; ++ct) acc[ct] = (f32x4){0.f, 0.f, 0.f, 0.f};

#pragma unroll
    for (int kb = 0; kb < 4; ++kb) {
#pragma unroll
        for (int ct = 0; ct < 8; ++ct) {
            bf16x8 bh = *reinterpret_cast<const bf16x8*>(&whi[((kb * 8 + ct) * 64 + lane) * 8]);
            bf16x8 bl = *reinterpret_cast<const bf16x8*>(&wlo[((kb * 8 + ct) * 64 + lane) * 8]);
            acc[ct] = __builtin_amdgcn_mfma_f32_16x16x32_bf16(Alo[kb], bh, acc[ct], 0, 0, 0);
            acc[ct] = __builtin_amdgcn_mfma_f32_16x16x32_bf16(Ahi[kb], bl, acc[ct], 0, 0, 0);
            acc[ct] = __builtin_amdgcn_mfma_f32_16x16x32_bf16(Ahi[kb], bh, acc[ct], 0, 0, 0);
        }
    }

#pragma unroll
    for (int q = 0; q < 4; ++q) {
        int n = rowbase + g * 4 + q;
        bool valid = (n < N);
        float p0s = 0.f, p1s = 0.f, p0d = 0.f, p1d = 0.f;
#pragma unroll
        for (int ct = 0; ct < 8; ++ct) {
            float h = acc[ct][q];
            if (valid) h1b[(long)n * HC1 + ct * 16 + li] = f2bf_rne(h);
            if (ct < 4) { p0s = fmaf(h, asr[ct], p0s); p0d = fmaf(h, adr[ct], p0d); }
            else        { p1s = fmaf(h, asr[ct], p1s); p1d = fmaf(h, adr[ct], p1d); }
        }
#pragma unroll
        for (int off = 8; off >= 1; off >>= 1) {
            p0s += __shfl_xor(p0s, off, 16);
            p1s += __shfl_xor(p1s, off, 16);
            p0d += __shfl_xor(p0d, off, 16);
            p1d += __shfl_xor(p1d, off, 16);
        }
        if (valid && li == 0) {
            as1[n * 2 + 0] = p0s; as1[n * 2 + 1] = p1s;
            ad1[n * 2 + 0] = p0d; ad1[n * 2 + 1] = p1d;
        }
    }
}

// ---------------------------------------------------------------------------
// FUSED CSR-build kernels: first nb_csr blocks do the CSR phase, remaining
// blocks run a gemm1 slice.
// ---------------------------------------------------------------------------
__global__ __launch_bounds__(256)
void f_bcnt(const int* __restrict__ ei, int* __restrict__ blockhist, int E, int NB,
            const float* __restrict__ x, const float* __restrict__ W1,
            const float* __restrict__ a_src, const float* __restrict__ a_dst,
            unsigned short* __restrict__ h1b, float* __restrict__ as1,
            float* __restrict__ ad1, int N, int nb_csr, int gemm_base) {
    __shared__ float4 smem[4096];   // 64 KB shared scratch
    int tid = threadIdx.x;
    if ((int)blockIdx.x >= nb_csr) {
        gemm1_body(x, W1, a_src, a_dst, h1b, as1, ad1, N,
                   gemm_base + blockIdx.x - nb_csr, smem);
        return;
    }
    int* h = (int*)smem;
    h[tid] = 0;
    __syncthreads();
    int base = blockIdx.x * EPB;
#pragma unroll
    for (int j = 0; j < EPB / 256; ++j) {
        int e = base + j * 256 + tid;
        if (e < E) atomicAdd(&h[ei[E + e] >> 8], 1);
    }
    __syncthreads();
    if (tid < NB) blockhist[blockIdx.x * NB + tid] = h[tid];
}

__global__ __launch_bounds__(256)
void f_colscan(int* __restrict__ blockhist, int* __restrict__ colsum, int EB, int NB,
               const float* __restrict__ x, const float* __restrict__ W1,
               const float* __restrict__ a_src, const float* __restrict__ a_dst,
               unsigned short* __restrict__ h1b, float* __restrict__ as1,
               float* __restrict__ ad1, int N, int nb_csr, int gemm_base) {
    __shared__ float4 smem[4096];
    int b = threadIdx.x;
    if ((int)blockIdx.x >= nb_csr) {
        gemm1_body(x, W1, a_src, a_dst, h1b, as1, ad1, N,
                   gemm_base + blockIdx.x - nb_csr, smem);
        return;
    }
    int* lds = (int*)smem;
    int t = blockIdx.x;       // bucket (column)
    int v = (b < EB) ? blockhist[b * NB + t] : 0;
    lds[b] = v;
    __syncthreads();
    for (int off = 1; off < 256; off <<= 1) {
        int u = (b >= off) ? lds[b - off] : 0;
        __syncthreads();
        lds[b] += u;
        __syncthreads();
    }
    if (b < EB) blockhist[b * NB + t] = lds[b] - v;   // excl offset within bucket
    if (b == 255) colsum[t] = lds[255];
}

// 1 block: exclusive scan of colsum -> bucket_base; + W2 prep.
__global__ __launch_bounds__(256)
void bscan2_kernel(const int* __restrict__ colsum, int* __restrict__ bucket_base,
                   int NB, const float* __restrict__ W2,
                   const float* __restrict__ a_src2, const float* __restrict__ a_dst2,
                   float* __restrict__ w2T, float* __restrict__ w2s,
                   float* __restrict__ w2d) {
    __shared__ int lds[256];
    int t = threadIdx.x;
    int v = (t < NB) ? colsum[t] : 0;
    lds[t] = v;
    __syncthreads();
    for (int off = 1; off < 256; off <<= 1) {
        int u = (t >= off) ? lds[t - off] : 0;
        __syncthreads();
        lds[t] += u;
        __syncthreads();
    }
    if (t < NB) bucket_base[t] = lds[t] - v;
    if (t == 255) bucket_base[NB] = lds[255];   // == E

    if (t < FIN) {
        float s = 0.f, d = 0.f;
#pragma unroll
        for (int c = 0; c < NCLS; ++c) {
            float w = W2[t * NCLS + c];
            w2T[c * FIN + t] = w;
            s = fmaf(w, a_src2[c], s);
            d = fmaf(w, a_dst2[c], d);
        }
        w2s[t] = s; w2d[t] = d;
    }
}

__global__ __launch_bounds__(256)
void f_binA(const int* __restrict__ ei, const int* __restrict__ blockhist,
            const int* __restrict__ bucket_base, int2* __restrict__ tmp,
            int E, int NB,
            const float* __restrict__ x, const float* __restrict__ W1,
            const float* __restrict__ a_src, const float* __restrict__ a_dst,
            unsigned short* __restrict__ h1b, float* __restrict__ as1,
            float* __restrict__ ad1, int N, int nb_csr, int gemm_base) {
    __shared__ float4 smem[4096];
    int tid = threadIdx.x;
    if ((int)blockIdx.x >= nb_csr) {
        gemm1_body(x, W1, a_src, a_dst, h1b, as1, ad1, N,
                   gemm_base + blockIdx.x - nb_csr, smem);
        return;
    }
    int* h  = (int*)smem;        // local cursors [256]
    int* bb = h + 256;           // global base per bucket [256]
    h[tid] = 0;
    if (tid < NB) bb[tid] = blockhist[blockIdx.x * NB + tid] + bucket_base[tid];
    __syncthreads();
    int base = blockIdx.x * EPB;
#pragma unroll
    for (int j = 0; j < EPB / 256; ++j) {
        int e = base + j * 256 + tid;
        if (e < E) {
            int s = ei[e], d = ei[E + e];
            int b = d >> 8;
            int r = atomicAdd(&h[b], 1);
            tmp[bb[b] + r] = make_int2(s, d);
        }
    }
}

__global__ __launch_bounds__(256)
void f_binB(const int2* __restrict__ tmp, const int* __restrict__ bucket_base,
            int* __restrict__ csr, int* __restrict__ eoffs, int E, int N,
            const float* __restrict__ x, const float* __restrict__ W1,
            const float* __restrict__ a_src, const float* __restrict__ a_dst,
            unsigned short* __restrict__ h1b, float* __restrict__ as1,
            float* __restrict__ ad1, int nb_csr, int gemm_base) {
    __shared__ float4 smem[4096];
    int t = threadIdx.x;
    if ((int)blockIdx.x >= nb_csr) {
        gemm1_body(x, W1, a_src, a_dst, h1b, as1, ad1, N,
                   gemm_base + blockIdx.x - nb_csr, smem);
        return;
    }
    int* cnt = (int*)smem;       // [256]
    int* lds = cnt + 256;        // [256]
    int* cur = cnt + 512;        // [256]
    int b = blockIdx.x;
    int lo = bucket_base[b], hi = bucket_base[b + 1];
    cnt[t] = 0;
    __syncthreads();
    for (int i = lo + t; i < hi; i += 256)
        atomicAdd(&cnt[tmp[i].y & 255], 1);
    __syncthreads();
    int v = cnt[t];
    lds[t] = v;
    __syncthreads();
    for (int off = 1; off < 256; off <<= 1) {
        int u = (t >= off) ? lds[t - off] : 0;
        __syncthreads();
        lds[t] += u;
        __syncthreads();
    }
    int excl = lds[t] - v;
    int node = b * 256 + t;
    if (node < N) eoffs[node] = lo + excl;
    if (b == 0 && t == 0) eoffs[N] = E;
    cur[t] = lo + excl;
    __syncthreads();
    for (int i = lo + t; i < hi; i += 256) {
        int2 e = tmp[i];
        int p = atomicAdd(&cur[e.y & 255], 1);
        csr[p] = e.x;
    }
}

// ---------------------------------------------------------------------------
// Layer 1 FUSED gather+softmax+ELU+GEMM2+alpha2, v3: 16 lanes x 8 cols per
// node (16 B dwordx4 gathers), 16 nodes per 256-block. Single edge pass, no
// max-subtraction. Epilogue: class-fold over 16 lanes (15 shfl) -> lane l
// holds z[l]; coalesced 64 B zout row store. No LDS/barriers.
// ---------------------------------------------------------------------------
__global__ __launch_bounds__(256)
void fgather1(const int* __restrict__ eoffs, const int* __restrict__ csr,
              const float* __restrict__ as_arr, const float* __restrict__ ad_arr,
              const unsigned short* __restrict__ h1b, const float* __restrict__ b1,
              const float* __restrict__ w2T, const float* __restrict__ w2s,
              const float* __restrict__ w2d,
              float* __restrict__ zout, float* __restrict__ as2,
              float* __restrict__ ad2, int N) {
    int tid = threadIdx.x;
    int g = tid >> 4;                // 0..15 node-group in block
    int l = tid & 15;                // lane in group: cols 8l..8l+7
    int n = blockIdx.x * 16 + g;
    if (n >= N) return;
    int head = l >> 3;               // cols 0-63 head0 (lanes 0-7), 64-127 head1
    int s0 = eoffs[n], s1 = eoffs[n + 1];

    float ad0 = ad_arr[2 * n], ad1v = ad_arr[2 * n + 1];
    float2 aself = *reinterpret_cast<const float2*>(&as_arr[2 * n]);
    float vs0 = aself.x + ad0;  vs0 = (vs0 >= 0.f) ? vs0 : NEG_SLOPE * vs0;
    float vs1 = aself.y + ad1v; vs1 = (vs1 >= 0.f) ? vs1 : NEG_SLOPE * vs1;
    float adn = head ? ad1v : ad0;

    float ps = __expf(head ? vs1 : vs0);
    uint4 us = *reinterpret_cast<const uint4*>(&h1b[((long)n << 7) + 8 * l]);
    float acc[8];
    acc[0] = bflo(us.x) * ps; acc[1] = bfhi(us.x) * ps;
    acc[2] = bflo(us.y) * ps; acc[3] = bfhi(us.y) * ps;
    acc[4] = bflo(us.z) * ps; acc[5] = bfhi(us.z) * ps;
    acc[6] = bflo(us.w) * ps; acc[7] = bfhi(us.w) * ps;
    float den = ps;

    int i = s0;
    for (; i + 4 <= s1; i += 4) {
        int sa = csr[i], sb = csr[i + 1], sc = csr[i + 2], sd = csr[i + 3];
        float aa = as_arr[2 * sa + head];
        float ab = as_arr[2 * sb + head];
        float ac = as_arr[2 * sc + head];
        float ad = as_arr[2 * sd + head];
        uint4 ua = *reinterpret_cast<const uint4*>(&h1b[((long)sa << 7) + 8 * l]);
        uint4 ub = *reinterpret_cast<const uint4*>(&h1b[((long)sb << 7) + 8 * l]);
        uint4 uc = *reinterpret_cast<const uint4*>(&h1b[((long)sc << 7) + 8 * l]);
        uint4 ud = *reinterpret_cast<const uint4*>(&h1b[((long)sd << 7) + 8 * l]);
        float va = aa + adn; va = (va >= 0.f) ? va : NEG_SLOPE * va;
        float vb = ab + adn; vb = (vb >= 0.f) ? vb : NEG_SLOPE * vb;
        float vc = ac + adn; vc = (vc >= 0.f) ? vc : NEG_SLOPE * vc;
        float vd = ad + adn; vd = (vd >= 0.f) ? vd : NEG_SLOPE * vd;
        float wa = __expf(va);
        float wb = __expf(vb);
        float wc = __expf(vc);
        float wd = __expf(vd);
        den += wa + wb + wc + wd;
        acc8(acc, ua, wa);
        acc8(acc, ub, wb);
        acc8(acc, uc, wc);
        acc8(acc, ud, wd);
    }
    for (; i < s1; ++i) {
        int s = csr[i];
        float av = as_arr[2 * s + head];
        uint4 u = *reinterpret_cast<const uint4*>(&h1b[((long)s << 7) + 8 * l]);
        float v = av + adn; v = (v >= 0.f) ? v : NEG_SLOPE * v;
        float w = __expf(v);
        den += w;
        acc8(acc, u, w);
    }
    float r = 1.f / (den + 1e-16f);
    int col = 8 * l;
    float o[8];
#pragma unroll
    for (int j = 0; j < 8; ++j) {
        float t2 = acc[j] * r + b1[col + j];
        o[j] = (t2 > 0.f) ? t2 : expm1f(t2);   // ELU
    }

    // as2/ad2 = h2 . (W2 @ a_src2), h2 . (W2 @ a_dst2)  -- 8 shfl
    float sa2 = 0.f, da2 = 0.f;
#pragma unroll
    for (int j = 0; j < 8; ++j) {
        sa2 = fmaf(o[j], w2s[col + j], sa2);
        da2 = fmaf(o[j], w2d[col + j], da2);
    }
#pragma unroll
    for (int off = 8; off >= 1; off >>= 1) {
        sa2 += __shfl_xor(sa2, off, 16);
        da2 += __shfl_xor(da2, off, 16);
    }
    if (l == 0) { as2[n] = sa2; ad2[n] = da2; }

    // z = h2 @ W2 via class-fold butterfly over 16 lanes (15 shfl);
    // lane l ends holding z[l]; coalesced row store.
    float zp[NCLS];
#pragma unroll
    for (int c = 0; c < NCLS; ++c) {
        const float* wc = &w2T[c * FIN + col];
        float t2 = 0.f;
#pragma unroll
        for (int j = 0; j < 8; ++j) t2 = fmaf(o[j], wc[j], t2);
        zp[c] = t2;
    }
    int bsel = (l >> 3) & 1;
    float z8[8];
#pragma unroll
    for (int j = 0; j < 8; ++j) {
        float send = bsel ? zp[j] : zp[j + 8];
        float keep = bsel ? zp[j + 8] : zp[j];
        z8[j] = keep + __shfl_xor(send, 8, 16);
    }
    bsel = (l >> 2) & 1;
    float z4v[4];
#pragma unroll
    for (int j = 0; j < 4; ++j) {
        float send = bsel ? z8[j] : z8[j + 4];
        float keep = bsel ? z8[j + 4] : z8[j];
        z4v[j] = keep + __shfl_xor(send, 4, 16);
    }
    bsel = (l >> 1) & 1;
    float z2v[2];
#pragma unroll
    for (int j = 0; j < 2; ++j) {
        float send = bsel ? z4v[j] : z4v[j + 2];
        float keep = bsel ? z4v[j + 2] : z4v[j];
        z2v[j] = keep + __shfl_xor(send, 2, 16);
    }
    bsel = l & 1;
    float z1v;
    {
        float send = bsel ? z2v[0] : z2v[1];
        float keep = bsel ? z2v[1] : z2v[0];
        z1v = keep + __shfl_xor(send, 1, 16);
    }
    zout[(long)n * NCLS + l] = z1v;   // lane l holds class l
}

// ---------------------------------------------------------------------------
// Layer 2 FUSED gather+softmax + bias + log_softmax (unchanged).
// ---------------------------------------------------------------------------
__global__ __launch_bounds__(256)
void fgather2(const int* __restrict__ eoffs, const int* __restrict__ csr,
              const float* __restrict__ as2, const float* __restrict__ ad2,
              const float* __restrict__ z, const float* __restrict__ b2,
              float* __restrict__ out, int N) {
    int g = threadIdx.x >> 4;
    int l = threadIdx.x & 15;
    int n = blockIdx.x * 16 + g;
    if (n >= N) return;
    int s0 = eoffs[n], s1 = eoffs[n + 1];
    float adn = ad2[n];
    float vs = as2[n] + adn; vs = (vs >= 0.f) ? vs : NEG_SLOPE * vs;

    float ps = __expf(vs);
    float acc = ps * z[(long)n * NCLS + l];
    float den = ps;
    int i = s0;
    for (; i + 4 <= s1; i += 4) {
        int sa = csr[i], sb = csr[i + 1], sc = csr[i + 2], sd = csr[i + 3];
        float aa = as2[sa], ab = as2[sb], ac = as2[sc], ad = as2[sd];
        float za = z[sa * NCLS + l];
        float zb = z[sb * NCLS + l];
        float zc = z[sc * NCLS + l];
        float zd = z[sd * NCLS + l];
        float va = aa + adn; va = (va >= 0.f) ? va : NEG_SLOPE * va;
        float vb = ab + adn; vb = (vb >= 0.f) ? vb : NEG_SLOPE * vb;
        float vc = ac + adn; vc = (vc >= 0.f) ? vc : NEG_SLOPE * vc;
        float vd = ad + adn; vd = (vd >= 0.f) ? vd : NEG_SLOPE * vd;
        float pa = __expf(va);
        float pb = __expf(vb);
        float pc = __expf(vc);
        float pd = __expf(vd);
        den += pa + pb + pc + pd;
        acc = fmaf(za, pa, acc);
        acc = fmaf(zb, pb, acc);
        acc = fmaf(zc, pc, acc);
        acc = fmaf(zd, pd, acc);
    }
    for (; i < s1; ++i) {
        int s = csr[i];
        float v = as2[s] + adn; v = (v >= 0.f) ? v : NEG_SLOPE * v;
        float p = __expf(v);
        den += p;
        acc = fmaf(z[s * NCLS + l], p, acc);
    }

    float o = acc / (den + 1e-16f) + b2[l];

    float mx = o;
#pragma unroll
    for (int off = 8; off >= 1; off >>= 1) mx = fmaxf(mx, __shfl_xor(mx, off, 16));
    float ex = __expf(o - mx);
    float sum = ex;
#pragma unroll
    for (int off = 8; off >= 1; off >>= 1) sum += __shfl_xor(sum, off, 16);
    out[(long)n * NCLS + l] = o - mx - __logf(sum);
}

// ---------------------------------------------------------------------------
extern "C" void kernel_launch(void* const* d_in, const int* in_sizes, int n_in,
                              void* d_out, int out_size, void* d_ws, size_t ws_size,
                              hipStream_t stream) {
    const float* x        = (const float*)d_in[0];
    const int*   ei       = (const int*)  d_in[1];
    // d_in[2] = edge_attr (unused by reference)
    const float* W1       = (const float*)d_in[3];
    const float* att_src1 = (const float*)d_in[4];
    const float* att_dst1 = (const float*)d_in[5];
    const float* b1       = (const float*)d_in[6];
    const float* W2       = (const float*)d_in[7];
    const float* att_src2 = (const float*)d_in[8];
    const float* att_dst2 = (const float*)d_in[9];
    const float* b2       = (const float*)d_in[10];
    float* out = (float*)d_out;

    const int N = in_sizes[0] / FIN;        // 50000
    const int E = in_sizes[1] / 2;          // 800000
    const int NB = (N + 255) >> 8;          // 196 buckets
    const int EB = (E + EPB - 1) / EPB;     // 196 edge blocks (<=256)
    const int GB = (N + 63) / 64;           // 782 gemm1 blocks

    // gemm1 block slices fused into the 4 parallel CSR kernels
    int q = GB / 4, rr = GB % 4;
    int g0 = q + (rr > 0 ? 1 : 0);
    int g1 = q + (rr > 1 ? 1 : 0);
    int g2 = q + (rr > 2 ? 1 : 0);
    int g3 = q;
    int b0 = 0, b1o = g0, b2o = g0 + g1, b3o = g0 + g1 + g2;

    // Workspace layout (bytes)
    char* ws = (char*)d_ws;
    size_t off = 0;
    auto alloc = [&](size_t bytes) { char* p = ws + off; off += (bytes + 255) & ~(size_t)255; return p; };
    int*    blockhist     = (int*)  alloc((size_t)EB * NB * 4);
    int*    colsum        = (int*)  alloc((size_t)NB * 4);
    int*    bucket_base   = (int*)  alloc((size_t)(NB + 1) * 4);
    int2*   tmp           = (int2*) alloc((size_t)E * 8);
    int*    csr           = (int*)  alloc((size_t)E * 4);
    int*    eoffs         = (int*)  alloc((size_t)(N + 1) * 4);
    unsigned short* h1b   = (unsigned short*)alloc((size_t)N * HC1 * 2);  // bf16
    float*  z             = (float*) alloc((size_t)N * NCLS * 4);
    float*  as1           = (float*) alloc((size_t)N * 2 * 4);
    float*  ad1           = (float*) alloc((size_t)N * 2 * 4);
    float*  as2           = (float*) alloc((size_t)N * 4);
    float*  ad2           = (float*) alloc((size_t)N * 4);
    float*  w2T           = (float*) alloc((size_t)NCLS * FIN * 4);
    float*  w2s           = (float*) alloc((size_t)FIN * 4);
    float*  w2d           = (float*) alloc((size_t)FIN * 4);
    (void)ws_size;

    f_bcnt<<<EB + g0, 256, 0, stream>>>(ei, blockhist, E, NB,
        x, W1, att_src1, att_dst1, h1b, as1, ad1, N, EB, b0);
    f_colscan<<<NB + g1, 256, 0, stream>>>(blockhist, colsum, EB, NB,
        x, W1, att_src1, att_dst1, h1b, as1, ad1, N, NB, b1o);
    bscan2_kernel<<<1, 256, 0, stream>>>(colsum, bucket_base, NB,
                                         W2, att_src2, att_dst2, w2T, w2s, w2d);
    f_binA<<<EB + g2, 256, 0, stream>>>(ei, blockhist, bucket_base, tmp, E, NB,
        x, W1, att_src1, att_dst1, h1b, as1, ad1, N, EB, b2o);
    f_binB<<<NB + g3, 256, 0, stream>>>(tmp, bucket_base, csr, eoffs, E, N,
        x, W1, att_src1, att_dst1, h1b, as1, ad1, NB, b3o);

    fgather1<<<(N + 15) / 16, 256, 0, stream>>>(
        eoffs, csr, as1, ad1, h1b, b1, w2T, w2s, w2d, z, as2, ad2, N);
    fgather2<<<(N + 15) / 16, 256, 0, stream>>>(eoffs, csr, as2, ad2, z, b2, out, N);
}

// Round 17
// 109.177 us; speedup vs baseline: 1.0312x; 1.0312x over previous
//
#include <hip/hip_runtime.h>
#include <math.h>

// Problem constants (match reference)
#define FIN   128
#define HC1   128   // H*C for layer 1
#define NCLS  16
#define NEG_SLOPE 0.2f

typedef __attribute__((ext_vector_type(8))) short bf16x8;
typedef __attribute__((ext_vector_type(4))) float f32x4;

__device__ __forceinline__ unsigned short f2bf_rne(float f) {
    unsigned int u = __float_as_uint(f);
    unsigned int r = u + 0x7FFFu + ((u >> 16) & 1u);
    return (unsigned short)(r >> 16);
}
__device__ __forceinline__ float bf2f(unsigned short h) {
    return __uint_as_float(((unsigned int)h) << 16);
}
__device__ __forceinline__ float bflo(unsigned int u) { return __uint_as_float(u << 16); }
__device__ __forceinline__ float bfhi(unsigned int u) { return __uint_as_float(u & 0xFFFF0000u); }

#define EPB 4096   // edges per block in bcnt/binA  (EB = ceil(E/EPB) must be <=256)

// ---------------------------------------------------------------------------
// gemm1 body (split-bf16 MFMA, h1=x@W1 -> bf16, fused alpha1 reductions).
// ---------------------------------------------------------------------------
__device__ __forceinline__
void gemm1_body(const float* __restrict__ x, const float* __restrict__ W,
                const float* __restrict__ a_src, const float* __restrict__ a_dst,
                unsigned short* __restrict__ h1b, float* __restrict__ as1,
                float* __restrict__ ad1, int N, int bid, float4* smem) {
    unsigned short* whi = (unsigned short*)smem;          // 32 KB
    unsigned short* wlo = whi + FIN * HC1;                // 32 KB
    int tid = threadIdx.x;

#pragma unroll
    for (int i = 0; i < 64; ++i) {
        int idx = tid + i * 256;            // 0..16383, coalesced
        int k = idx >> 7, c = idx & 127;
        float v = W[idx];
        unsigned short hb = f2bf_rne(v);
        unsigned short lb = f2bf_rne(v - bf2f(hb));
        int kb = k >> 5, kk = k & 31;
        int g = kk >> 3, j = kk & 7;
        int ct = c >> 4, li = c & 15;
        int off = ((kb * 8 + ct) * 64 + g * 16 + li) * 8 + j;
        whi[off] = hb;
        wlo[off] = lb;
    }

    int wid = tid >> 6, lane = tid & 63;
    int li = lane & 15, g = lane >> 4;
    int rowbase = bid * 64 + wid * 16;

    int arow = rowbase + li;
    if (arow >= N) arow = N - 1;            // clamp; invalid rows never stored
    const float* xp = x + (long)arow * FIN + g * 8;
    bf16x8 Ahi[4], Alo[4];
#pragma unroll
    for (int kb = 0; kb < 4; ++kb) {
        float4 v0 = *reinterpret_cast<const float4*>(xp + kb * 32);
        float4 v1 = *reinterpret_cast<const float4*>(xp + kb * 32 + 4);
        float vs0 = v0.x, vs1 = v0.y, vs2 = v0.z, vs3 = v0.w;
        float vs4 = v1.x, vs5 = v1.y, vs6 = v1.z, vs7 = v1.w;
        bf16x8 h8, l8;
        unsigned short hb;
        hb = f2bf_rne(vs0); h8[0] = (short)hb; l8[0] = (short)f2bf_rne(vs0 - bf2f(hb));
        hb = f2bf_rne(vs1); h8[1] = (short)hb; l8[1] = (short)f2bf_rne(vs1 - bf2f(hb));
        hb = f2bf_rne(vs2); h8[2] = (short)hb; l8[2] = (short)f2bf_rne(vs2 - bf2f(hb));
        hb = f2bf_rne(vs3); h8[3] = (short)hb; l8[3] = (short)f2bf_rne(vs3 - bf2f(hb));
        hb = f2bf_rne(vs4); h8[4] = (short)hb; l8[4] = (short)f2bf_rne(vs4 - bf2f(hb));
        hb = f2bf_rne(vs5); h8[5] = (short)hb; l8[5] = (short)f2bf_rne(vs5 - bf2f(hb));
        hb = f2bf_rne(vs6); h8[6] = (short)hb; l8[6] = (short)f2bf_rne(vs6 - bf2f(hb));
        hb = f2bf_rne(vs7); h8[7] = (short)hb; l8[7] = (short)f2bf_rne(vs7 - bf2f(hb));
        Ahi[kb] = h8; Alo[kb] = l8;
    }

    float asr[8], adr[8];
#pragma unroll
    for (int ct = 0; ct < 8; ++ct) {
        asr[ct] = a_src[ct * 16 + li];
        adr[ct] = a_dst[ct * 16 + li];
    }

    __syncthreads();

    f32x4 acc[8];
#pragma unroll
    for (int ct = 0; ct < 8; ++ct) acc[ct] = (f32x4){0.f, 0.f, 0.f, 0.f};

#pragma unroll
    for (int kb = 0; kb < 4; ++kb) {
#pragma unroll
        for (int ct = 0; ct < 8; ++ct) {
            bf16x8 bh = *reinterpret_cast<const bf16x8*>(&whi[((kb * 8 + ct) * 64 + lane) * 8]);
            bf16x8 bl = *reinterpret_cast<const bf16x8*>(&wlo[((kb * 8 + ct) * 64 + lane) * 8]);
            acc[ct] = __builtin_amdgcn_mfma_f32_16x16x32_bf16(Alo[kb], bh, acc[ct], 0, 0, 0);
            acc[ct] = __builtin_amdgcn_mfma_f32_16x16x32_bf16(Ahi[kb], bl, acc[ct], 0, 0, 0);
            acc[ct] = __builtin_amdgcn_mfma_f32_16x16x32_bf16(Ahi[kb], bh, acc[ct], 0, 0, 0);
        }
    }

#pragma unroll
    for (int q = 0; q < 4; ++q) {
        int n = rowbase + g * 4 + q;
        bool valid = (n < N);
        float p0s = 0.f, p1s = 0.f, p0d = 0.f, p1d = 0.f;
#pragma unroll
        for (int ct = 0; ct < 8; ++ct) {
            float h = acc[ct][q];
            if (valid) h1b[(long)n * HC1 + ct * 16 + li] = f2bf_rne(h);
            if (ct < 4) { p0s = fmaf(h, asr[ct], p0s); p0d = fmaf(h, adr[ct], p0d); }
            else        { p1s = fmaf(h, asr[ct], p1s); p1d = fmaf(h, adr[ct], p1d); }
        }
#pragma unroll
        for (int off = 8; off >= 1; off >>= 1) {
            p0s += __shfl_xor(p0s, off, 16);
            p1s += __shfl_xor(p1s, off, 16);
            p0d += __shfl_xor(p0d, off, 16);
            p1d += __shfl_xor(p1d, off, 16);
        }
        if (valid && li == 0) {
            as1[n * 2 + 0] = p0s; as1[n * 2 + 1] = p1s;
            ad1[n * 2 + 0] = p0d; ad1[n * 2 + 1] = p1d;
        }
    }
}

// ---------------------------------------------------------------------------
// FUSED CSR-build kernels: first nb_csr blocks do the CSR phase, remaining
// blocks run a gemm1 slice. tmp packed: (src<<8)|(dst&255), src < 2^24.
// ---------------------------------------------------------------------------
__global__ __launch_bounds__(256)
void f_bcnt(const int* __restrict__ ei, int* __restrict__ blockhist, int E, int NB,
            const float* __restrict__ x, const float* __restrict__ W1,
            const float* __restrict__ a_src, const float* __restrict__ a_dst,
            unsigned short* __restrict__ h1b, float* __restrict__ as1,
            float* __restrict__ ad1, int N, int nb_csr, int gemm_base) {
    __shared__ float4 smem[4096];   // 64 KB shared scratch
    int tid = threadIdx.x;
    if ((int)blockIdx.x >= nb_csr) {
        gemm1_body(x, W1, a_src, a_dst, h1b, as1, ad1, N,
                   gemm_base + blockIdx.x - nb_csr, smem);
        return;
    }
    int* h = (int*)smem;
    h[tid] = 0;
    __syncthreads();
    int base = blockIdx.x * EPB;
#pragma unroll
    for (int j = 0; j < EPB / 256; ++j) {
        int e = base + j * 256 + tid;
        if (e < E) atomicAdd(&h[ei[E + e] >> 8], 1);
    }
    __syncthreads();
    if (tid < NB) blockhist[blockIdx.x * NB + tid] = h[tid];
}

__global__ __launch_bounds__(256)
void f_colscan(int* __restrict__ blockhist, int* __restrict__ colsum, int EB, int NB,
               const float* __restrict__ x, const float* __restrict__ W1,
               const float* __restrict__ a_src, const float* __restrict__ a_dst,
               unsigned short* __restrict__ h1b, float* __restrict__ as1,
               float* __restrict__ ad1, int N, int nb_csr, int gemm_base) {
    __shared__ float4 smem[4096];
    int b = threadIdx.x;
    if ((int)blockIdx.x >= nb_csr) {
        gemm1_body(x, W1, a_src, a_dst, h1b, as1, ad1, N,
                   gemm_base + blockIdx.x - nb_csr, smem);
        return;
    }
    int* lds = (int*)smem;
    int t = blockIdx.x;       // bucket (column)
    int v = (b < EB) ? blockhist[b * NB + t] : 0;
    lds[b] = v;
    __syncthreads();
    for (int off = 1; off < 256; off <<= 1) {
        int u = (b >= off) ? lds[b - off] : 0;
        __syncthreads();
        lds[b] += u;
        __syncthreads();
    }
    if (b < EB) blockhist[b * NB + t] = lds[b] - v;   // excl offset within bucket
    if (b == 255) colsum[t] = lds[255];
}

// 1 block: exclusive scan of colsum -> bucket_base; + W2 prep.
__global__ __launch_bounds__(256)
void bscan2_kernel(const int* __restrict__ colsum, int* __restrict__ bucket_base,
                   int NB, const float* __restrict__ W2,
                   const float* __restrict__ a_src2, const float* __restrict__ a_dst2,
                   float* __restrict__ w2T, float* __restrict__ w2s,
                   float* __restrict__ w2d) {
    __shared__ int lds[256];
    int t = threadIdx.x;
    int v = (t < NB) ? colsum[t] : 0;
    lds[t] = v;
    __syncthreads();
    for (int off = 1; off < 256; off <<= 1) {
        int u = (t >= off) ? lds[t - off] : 0;
        __syncthreads();
        lds[t] += u;
        __syncthreads();
    }
    if (t < NB) bucket_base[t] = lds[t] - v;
    if (t == 255) bucket_base[NB] = lds[255];   // == E

    if (t < FIN) {
        float s = 0.f, d = 0.f;
#pragma unroll
        for (int c = 0; c < NCLS; ++c) {
            float w = W2[t * NCLS + c];
            w2T[c * FIN + t] = w;
            s = fmaf(w, a_src2[c], s);
            d = fmaf(w, a_dst2[c], d);
        }
        w2s[t] = s; w2d[t] = d;
    }
}

__global__ __launch_bounds__(256)
void f_binA(const int* __restrict__ ei, const int* __restrict__ blockhist,
            const int* __restrict__ bucket_base, int* __restrict__ tmp,
            int E, int NB,
            const float* __restrict__ x, const float* __restrict__ W1,
            const float* __restrict__ a_src, const float* __restrict__ a_dst,
            unsigned short* __restrict__ h1b, float* __restrict__ as1,
            float* __restrict__ ad1, int N, int nb_csr, int gemm_base) {
    __shared__ float4 smem[4096];
    int tid = threadIdx.x;
    if ((int)blockIdx.x >= nb_csr) {
        gemm1_body(x, W1, a_src, a_dst, h1b, as1, ad1, N,
                   gemm_base + blockIdx.x - nb_csr, smem);
        return;
    }
    int* h  = (int*)smem;        // local cursors [256]
    int* bb = h + 256;           // global base per bucket [256]
    h[tid] = 0;
    if (tid < NB) bb[tid] = blockhist[blockIdx.x * NB + tid] + bucket_base[tid];
    __syncthreads();
    int base = blockIdx.x * EPB;
#pragma unroll
    for (int j = 0; j < EPB / 256; ++j) {
        int e = base + j * 256 + tid;
        if (e < E) {
            int s = ei[e], d = ei[E + e];
            int b = d >> 8;
            int r = atomicAdd(&h[b], 1);
            tmp[bb[b] + r] = (s << 8) | (d & 255);   // packed
        }
    }
}

__global__ __launch_bounds__(256)
void f_binB(const int* __restrict__ tmp, const int* __restrict__ bucket_base,
            int* __restrict__ csr, int* __restrict__ eoffs, int E, int N,
            const float* __restrict__ x, const float* __restrict__ W1,
            const float* __restrict__ a_src, const float* __restrict__ a_dst,
            unsigned short* __restrict__ h1b, float* __restrict__ as1,
            float* __restrict__ ad1, int nb_csr, int gemm_base) {
    __shared__ float4 smem[4096];
    int t = threadIdx.x;
    if ((int)blockIdx.x >= nb_csr) {
        gemm1_body(x, W1, a_src, a_dst, h1b, as1, ad1, N,
                   gemm_base + blockIdx.x - nb_csr, smem);
        return;
    }
    int* cnt = (int*)smem;       // [256]
    int* lds = cnt + 256;        // [256]
    int* cur = cnt + 512;        // [256]
    int b = blockIdx.x;
    int lo = bucket_base[b], hi = bucket_base[b + 1];
    cnt[t] = 0;
    __syncthreads();
    for (int i = lo + t; i < hi; i += 256)
        atomicAdd(&cnt[tmp[i] & 255], 1);
    __syncthreads();
    int v = cnt[t];
    lds[t] = v;
    __syncthreads();
    for (int off = 1; off < 256; off <<= 1) {
        int u = (t >= off) ? lds[t - off] : 0;
        __syncthreads();
        lds[t] += u;
        __syncthreads();
    }
    int excl = lds[t] - v;
    int node = b * 256 + t;
    if (node < N) eoffs[node] = lo + excl;
    if (b == 0 && t == 0) eoffs[N] = E;
    cur[t] = lo + excl;
    __syncthreads();
    for (int i = lo + t; i < hi; i += 256) {
        int e = tmp[i];
        int p = atomicAdd(&cur[e & 255], 1);
        csr[p] = ((unsigned int)e) >> 8;     // src
    }
}

// ---------------------------------------------------------------------------
// Layer 1 FUSED gather+softmax+ELU+GEMM2+alpha2 (32 lanes/node, 8 nodes per
// 256-block — R15 structure) with edge loop unrolled x8 for deeper MLP.
// Single edge pass, no max-subtraction; class-fold butterfly epilogue.
// ---------------------------------------------------------------------------
__global__ __launch_bounds__(256)
void fgather1(const int* __restrict__ eoffs, const int* __restrict__ csr,
              const float* __restrict__ as_arr, const float* __restrict__ ad_arr,
              const unsigned short* __restrict__ h1b, const float* __restrict__ b1,
              const float* __restrict__ w2T, const float* __restrict__ w2s,
              const float* __restrict__ w2d,
              float* __restrict__ zout, float* __restrict__ as2,
              float* __restrict__ ad2, int N) {
    int tid = threadIdx.x;
    int g = tid >> 5;                // 0..7 node-group in block (32-lane aligned)
    int l = tid & 31;                // lane in group: cols 4l..4l+3
    int n = blockIdx.x * 8 + g;
    if (n >= N) return;
    int head = l >> 4;
    int s0 = eoffs[n], s1 = eoffs[n + 1];

    float ad0 = ad_arr[2 * n], ad1v = ad_arr[2 * n + 1];
    float2 aself = *reinterpret_cast<const float2*>(&as_arr[2 * n]);
    float vs0 = aself.x + ad0;  vs0 = (vs0 >= 0.f) ? vs0 : NEG_SLOPE * vs0;
    float vs1 = aself.y + ad1v; vs1 = (vs1 >= 0.f) ? vs1 : NEG_SLOPE * vs1;
    float adn = head ? ad1v : ad0;

    float ps = __expf(head ? vs1 : vs0);
    uint2 us = *reinterpret_cast<const uint2*>(&h1b[((long)n << 7) + 4 * l]);
    float4 acc;
    acc.x = bflo(us.x) * ps; acc.y = bfhi(us.x) * ps;
    acc.z = bflo(us.y) * ps; acc.w = bfhi(us.y) * ps;
    float den = ps;

    int i = s0;
    for (; i + 8 <= s1; i += 8) {
        int se[8];
#pragma unroll
        for (int j = 0; j < 8; ++j) se[j] = csr[i + j];
        float av[8];
#pragma unroll
        for (int j = 0; j < 8; ++j) av[j] = as_arr[2 * se[j] + head];
        uint2 u[8];
#pragma unroll
        for (int j = 0; j < 8; ++j)
            u[j] = *reinterpret_cast<const uint2*>(&h1b[((long)se[j] << 7) + 4 * l]);
        float w[8];
#pragma unroll
        for (int j = 0; j < 8; ++j) {
            float v = av[j] + adn; v = (v >= 0.f) ? v : NEG_SLOPE * v;
            w[j] = __expf(v);
            den += w[j];
        }
#pragma unroll
        for (int j = 0; j < 8; ++j) {
            acc.x = fmaf(bflo(u[j].x), w[j], acc.x);
            acc.y = fmaf(bfhi(u[j].x), w[j], acc.y);
            acc.z = fmaf(bflo(u[j].y), w[j], acc.z);
            acc.w = fmaf(bfhi(u[j].y), w[j], acc.w);
        }
    }
    for (; i + 4 <= s1; i += 4) {
        int sa = csr[i], sb = csr[i + 1], sc = csr[i + 2], sd = csr[i + 3];
        float aa = as_arr[2 * sa + head];
        float ab = as_arr[2 * sb + head];
        float ac = as_arr[2 * sc + head];
        float ad = as_arr[2 * sd + head];
        uint2 ua = *reinterpret_cast<const uint2*>(&h1b[((long)sa << 7) + 4 * l]);
        uint2 ub = *reinterpret_cast<const uint2*>(&h1b[((long)sb << 7) + 4 * l]);
        uint2 uc = *reinterpret_cast<const uint2*>(&h1b[((long)sc << 7) + 4 * l]);
        uint2 ud = *reinterpret_cast<const uint2*>(&h1b[((long)sd << 7) + 4 * l]);
        float va = aa + adn; va = (va >= 0.f) ? va : NEG_SLOPE * va;
        float vb = ab + adn; vb = (vb >= 0.f) ? vb : NEG_SLOPE * vb;
        float vc = ac + adn; vc = (vc >= 0.f) ? vc : NEG_SLOPE * vc;
        float vd = ad + adn; vd = (vd >= 0.f) ? vd : NEG_SLOPE * vd;
        float wa = __expf(va);
        float wb = __expf(vb);
        float wc = __expf(vc);
        float wd = __expf(vd);
        den += wa + wb + wc + wd;
        acc.x = fmaf(bflo(ua.x), wa, acc.x); acc.y = fmaf(bfhi(ua.x), wa, acc.y);
        acc.z = fmaf(bflo(ua.y), wa, acc.z); acc.w = fmaf(bfhi(ua.y), wa, acc.w);
        acc.x = fmaf(bflo(ub.x), wb, acc.x); acc.y = fmaf(bfhi(ub.x), wb, acc.y);
        acc.z = fmaf(bflo(ub.y), wb, acc.z); acc.w = fmaf(bfhi(ub.y), wb, acc.w);
        acc.x = fmaf(bflo(uc.x), wc, acc.x); acc.y = fmaf(bfhi(uc.x), wc, acc.y);
        acc.z = fmaf(bflo(uc.y), wc, acc.z); acc.w = fmaf(bfhi(uc.y), wc, acc.w);
        acc.x = fmaf(bflo(ud.x), wd, acc.x); acc.y = fmaf(bfhi(ud.x), wd, acc.y);
        acc.z = fmaf(bflo(ud.y), wd, acc.z); acc.w = fmaf(bfhi(ud.y), wd, acc.w);
    }
    for (; i < s1; ++i) {
        int s = csr[i];
        float av = as_arr[2 * s + head];
        uint2 u = *reinterpret_cast<const uint2*>(&h1b[((long)s << 7) + 4 * l]);
        float v = av + adn; v = (v >= 0.f) ? v : NEG_SLOPE * v;
        float w = __expf(v);
        den += w;
        acc.x = fmaf(bflo(u.x), w, acc.x); acc.y = fmaf(bfhi(u.x), w, acc.y);
        acc.z = fmaf(bflo(u.y), w, acc.z); acc.w = fmaf(bfhi(u.y), w, acc.w);
    }
    float r = 1.f / (den + 1e-16f);
    int col = 4 * l;
    float4 bb = *reinterpret_cast<const float4*>(&b1[col]);
    float4 o;
    o.x = acc.x * r + bb.x; o.y = acc.y * r + bb.y;
    o.z = acc.z * r + bb.z; o.w = acc.w * r + bb.w;
    o.x = (o.x > 0.f) ? o.x : expm1f(o.x);
    o.y = (o.y > 0.f) ? o.y : expm1f(o.y);
    o.z = (o.z > 0.f) ? o.z : expm1f(o.z);
    o.w = (o.w > 0.f) ? o.w : expm1f(o.w);

    // as2/ad2 = h2 . (W2 @ a_src2), h2 . (W2 @ a_dst2)  -- 10 shfl
    float4 ws4 = *reinterpret_cast<const float4*>(&w2s[col]);
    float4 wd4 = *reinterpret_cast<const float4*>(&w2d[col]);
    float sa2 = o.x * ws4.x + o.y * ws4.y + o.z * ws4.z + o.w * ws4.w;
    float da2 = o.x * wd4.x + o.y * wd4.y + o.z * wd4.z + o.w * wd4.w;
#pragma unroll
    for (int off = 16; off >= 1; off >>= 1) {
        sa2 += __shfl_xor(sa2, off, 32);
        da2 += __shfl_xor(da2, off, 32);
    }
    if (l == 0) { as2[n] = sa2; ad2[n] = da2; }

    // z = h2 @ W2 via class-fold butterfly (16 shfl total).
    float zp[NCLS];
#pragma unroll
    for (int c = 0; c < NCLS; ++c) {
        float4 w4 = *reinterpret_cast<const float4*>(&w2T[c * FIN + col]);
        zp[c] = o.x * w4.x + o.y * w4.y + o.z * w4.z + o.w * w4.w;
    }
    int bsel = (l >> 4) & 1;
    float z8[8];
#pragma unroll
    for (int j = 0; j < 8; ++j) {
        float send = bsel ? zp[j] : zp[j + 8];
        float keep = bsel ? zp[j + 8] : zp[j];
        z8[j] = keep + __shfl_xor(send, 16, 32);
    }
    bsel = (l >> 3) & 1;
    float z4v[4];
#pragma unroll
    for (int j = 0; j < 4; ++j) {
        float send = bsel ? z8[j] : z8[j + 4];
        float keep = bsel ? z8[j + 4] : z8[j];
        z4v[j] = keep + __shfl_xor(send, 8, 32);
    }
    bsel = (l >> 2) & 1;
    float z2v[2];
#pragma unroll
    for (int j = 0; j < 2; ++j) {
        float send = bsel ? z4v[j] : z4v[j + 2];
        float keep = bsel ? z4v[j + 2] : z4v[j];
        z2v[j] = keep + __shfl_xor(send, 4, 32);
    }
    bsel = (l >> 1) & 1;
    float z1v;
    {
        float send = bsel ? z2v[0] : z2v[1];
        float keep = bsel ? z2v[1] : z2v[0];
        z1v = keep + __shfl_xor(send, 2, 32);
    }
    z1v += __shfl_xor(z1v, 1, 32);
    if (!(l & 1)) zout[(long)n * NCLS + ((l >> 1) & 15)] = z1v;
}

// ---------------------------------------------------------------------------
// Layer 2 FUSED gather+softmax + bias + log_softmax (unchanged).
// ---------------------------------------------------------------------------
__global__ __launch_bounds__(256)
void fgather2(const int* __restrict__ eoffs, const int* __restrict__ csr,
              const float* __restrict__ as2, const float* __restrict__ ad2,
              const float* __restrict__ z, const float* __restrict__ b2,
              float* __restrict__ out, int N) {
    int g = threadIdx.x >> 4;
    int l = threadIdx.x & 15;
    int n = blockIdx.x * 16 + g;
    if (n >= N) return;
    int s0 = eoffs[n], s1 = eoffs[n + 1];
    float adn = ad2[n];
    float vs = as2[n] + adn; vs = (vs >= 0.f) ? vs : NEG_SLOPE * vs;

    float ps = __expf(vs);
    float acc = ps * z[(long)n * NCLS + l];
    float den = ps;
    int i = s0;
    for (; i + 4 <= s1; i += 4) {
        int sa = csr[i], sb = csr[i + 1], sc = csr[i + 2], sd = csr[i + 3];
        float aa = as2[sa], ab = as2[sb], ac = as2[sc], ad = as2[sd];
        float za = z[sa * NCLS + l];
        float zb = z[sb * NCLS + l];
        float zc = z[sc * NCLS + l];
        float zd = z[sd * NCLS + l];
        float va = aa + adn; va = (va >= 0.f) ? va : NEG_SLOPE * va;
        float vb = ab + adn; vb = (vb >= 0.f) ? vb : NEG_SLOPE * vb;
        float vc = ac + adn; vc = (vc >= 0.f) ? vc : NEG_SLOPE * vc;
        float vd = ad + adn; vd = (vd >= 0.f) ? vd : NEG_SLOPE * vd;
        float pa = __expf(va);
        float pb = __expf(vb);
        float pc = __expf(vc);
        float pd = __expf(vd);
        den += pa + pb + pc + pd;
        acc = fmaf(za, pa, acc);
        acc = fmaf(zb, pb, acc);
        acc = fmaf(zc, pc, acc);
        acc = fmaf(zd, pd, acc);
    }
    for (; i < s1; ++i) {
        int s = csr[i];
        float v = as2[s] + adn; v = (v >= 0.f) ? v : NEG_SLOPE * v;
        float p = __expf(v);
        den += p;
        acc = fmaf(z[s * NCLS + l], p, acc);
    }

    float o = acc / (den + 1e-16f) + b2[l];

    float mx = o;
#pragma unroll
    for (int off = 8; off >= 1; off >>= 1) mx = fmaxf(mx, __shfl_xor(mx, off, 16));
    float ex = __expf(o - mx);
    float sum = ex;
#pragma unroll
    for (int off = 8; off >= 1; off >>= 1) sum += __shfl_xor(sum, off, 16);
    out[(long)n * NCLS + l] = o - mx - __logf(sum);
}

// ---------------------------------------------------------------------------
extern "C" void kernel_launch(void* const* d_in, const int* in_sizes, int n_in,
                              void* d_out, int out_size, void* d_ws, size_t ws_size,
                              hipStream_t stream) {
    const float* x        = (const float*)d_in[0];
    const int*   ei       = (const int*)  d_in[1];
    // d_in[2] = edge_attr (unused by reference)
    const float* W1       = (const float*)d_in[3];
    const float* att_src1 = (const float*)d_in[4];
    const float* att_dst1 = (const float*)d_in[5];
    const float* b1       = (const float*)d_in[6];
    const float* W2       = (const float*)d_in[7];
    const float* att_src2 = (const float*)d_in[8];
    const float* att_dst2 = (const float*)d_in[9];
    const float* b2       = (const float*)d_in[10];
    float* out = (float*)d_out;

    const int N = in_sizes[0] / FIN;        // 50000
    const int E = in_sizes[1] / 2;          // 800000
    const int NB = (N + 255) >> 8;          // 196 buckets
    const int EB = (E + EPB - 1) / EPB;     // 196 edge blocks (<=256)
    const int GB = (N + 63) / 64;           // 782 gemm1 blocks

    // gemm1 block slices fused into the 4 parallel CSR kernels
    int q = GB / 4, rr = GB % 4;
    int g0 = q + (rr > 0 ? 1 : 0);
    int g1 = q + (rr > 1 ? 1 : 0);
    int g2 = q + (rr > 2 ? 1 : 0);
    int g3 = q;
    int b0 = 0, b1o = g0, b2o = g0 + g1, b3o = g0 + g1 + g2;

    // Workspace layout (bytes)
    char* ws = (char*)d_ws;
    size_t off = 0;
    auto alloc = [&](size_t bytes) { char* p = ws + off; off += (bytes + 255) & ~(size_t)255; return p; };
    int*    blockhist     = (int*)  alloc((size_t)EB * NB * 4);
    int*    colsum        = (int*)  alloc((size_t)NB * 4);
    int*    bucket_base   = (int*)  alloc((size_t)(NB + 1) * 4);
    int*    tmp           = (int*)  alloc((size_t)E * 4);    // packed (src<<8)|dst&255
    int*    csr           = (int*)  alloc((size_t)E * 4);
    int*    eoffs         = (int*)  alloc((size_t)(N + 1) * 4);
    unsigned short* h1b   = (unsigned short*)alloc((size_t)N * HC1 * 2);  // bf16
    float*  z             = (float*) alloc((size_t)N * NCLS * 4);
    float*  as1           = (float*) alloc((size_t)N * 2 * 4);
    float*  ad1           = (float*) alloc((size_t)N * 2 * 4);
    float*  as2           = (float*) alloc((size_t)N * 4);
    float*  ad2           = (float*) alloc((size_t)N * 4);
    float*  w2T           = (float*) alloc((size_t)NCLS * FIN * 4);
    float*  w2s           = (float*) alloc((size_t)FIN * 4);
    float*  w2d           = (float*) alloc((size_t)FIN * 4);
    (void)ws_size;

    f_bcnt<<<EB + g0, 256, 0, stream>>>(ei, blockhist, E, NB,
        x, W1, att_src1, att_dst1, h1b, as1, ad1, N, EB, b0);
    f_colscan<<<NB + g1, 256, 0, stream>>>(blockhist, colsum, EB, NB,
        x, W1, att_src1, att_dst1, h1b, as1, ad1, N, NB, b1o);
    bscan2_kernel<<<1, 256, 0, stream>>>(colsum, bucket_base, NB,
                                         W2, att_src2, att_dst2, w2T, w2s, w2d);
    f_binA<<<EB + g2, 256, 0, stream>>>(ei, blockhist, bucket_base, tmp, E, NB,
        x, W1, att_src1, att_dst1, h1b, as1, ad1, N, EB, b2o);
    f_binB<<<NB + g3, 256, 0, stream>>>(tmp, bucket_base, csr, eoffs, E, N,
        x, W1, att_src1, att_dst1, h1b, as1, ad1, NB, b3o);

    fgather1<<<(N + 7) / 8, 256, 0, stream>>>(
        eoffs, csr, as1, ad1, h1b, b1, w2T, w2s, w2d, z, as2, ad2, N);
    fgather2<<<(N + 15) / 16, 256, 0, stream>>>(eoffs, csr, as2, ad2, z, b2, out, N);
}

// Round 18
// 101.818 us; speedup vs baseline: 1.1058x; 1.0723x over previous
//
#include <hip/hip_runtime.h>
#include <math.h>

// Problem constants (match reference)
#define FIN   128
#define HC1   128   // H*C for layer 1
#define NCLS  16
#define NEG_SLOPE 0.2f

typedef __attribute__((ext_vector_type(8))) short bf16x8;
typedef __attribute__((ext_vector_type(4))) float f32x4;
typedef __attribute__((ext_vector_type(2))) float f32x2;

__device__ __forceinline__ unsigned short f2bf_rne(float f) {
    unsigned int u = __float_as_uint(f);
    unsigned int r = u + 0x7FFFu + ((u >> 16) & 1u);
    return (unsigned short)(r >> 16);
}
__device__ __forceinline__ float bf2f(unsigned short h) {
    return __uint_as_float(((unsigned int)h) << 16);
}

// fp8 e4m3 encode via HW converter (round-trips with the decode below).
__device__ __forceinline__ unsigned char f2fp8(float v) {
    int p = __builtin_amdgcn_cvt_pk_fp8_f32(v, v, 0, false);
    return (unsigned char)(p & 0xFF);
}

#define EPB 4096   // edges per block in bcnt/binA  (EB = ceil(E/EPB) must be <=256)

// ---------------------------------------------------------------------------
// gemm1 body (split-bf16 MFMA, h1=x@W1 -> fp8 e4m3, fused alpha1 reductions).
// ---------------------------------------------------------------------------
__device__ __forceinline__
void gemm1_body(const float* __restrict__ x, const float* __restrict__ W,
                const float* __restrict__ a_src, const float* __restrict__ a_dst,
                unsigned char* __restrict__ h1q, float* __restrict__ as1,
                float* __restrict__ ad1, int N, int bid, float4* smem) {
    unsigned short* whi = (unsigned short*)smem;          // 32 KB
    unsigned short* wlo = whi + FIN * HC1;                // 32 KB
    int tid = threadIdx.x;

#pragma unroll
    for (int i = 0; i < 64; ++i) {
        int idx = tid + i * 256;            // 0..16383, coalesced
        int k = idx >> 7, c = idx & 127;
        float v = W[idx];
        unsigned short hb = f2bf_rne(v);
        unsigned short lb = f2bf_rne(v - bf2f(hb));
        int kb = k >> 5, kk = k & 31;
        int g = kk >> 3, j = kk & 7;
        int ct = c >> 4, li = c & 15;
        int off = ((kb * 8 + ct) * 64 + g * 16 + li) * 8 + j;
        whi[off] = hb;
        wlo[off] = lb;
    }

    int wid = tid >> 6, lane = tid & 63;
    int li = lane & 15, g = lane >> 4;
    int rowbase = bid * 64 + wid * 16;

    int arow = rowbase + li;
    if (arow >= N) arow = N - 1;            // clamp; invalid rows never stored
    const float* xp = x + (long)arow * FIN + g * 8;
    bf16x8 Ahi[4], Alo[4];
#pragma unroll
    for (int kb = 0; kb < 4; ++kb) {
        float4 v0 = *reinterpret_cast<const float4*>(xp + kb * 32);
        float4 v1 = *reinterpret_cast<const float4*>(xp + kb * 32 + 4);
        float vs0 = v0.x, vs1 = v0.y, vs2 = v0.z, vs3 = v0.w;
        float vs4 = v1.x, vs5 = v1.y, vs6 = v1.z, vs7 = v1.w;
        bf16x8 h8, l8;
        unsigned short hb;
        hb = f2bf_rne(vs0); h8[0] = (short)hb; l8[0] = (short)f2bf_rne(vs0 - bf2f(hb));
        hb = f2bf_rne(vs1); h8[1] = (short)hb; l8[1] = (short)f2bf_rne(vs1 - bf2f(hb));
        hb = f2bf_rne(vs2); h8[2] = (short)hb; l8[2] = (short)f2bf_rne(vs2 - bf2f(hb));
        hb = f2bf_rne(vs3); h8[3] = (short)hb; l8[3] = (short)f2bf_rne(vs3 - bf2f(hb));
        hb = f2bf_rne(vs4); h8[4] = (short)hb; l8[4] = (short)f2bf_rne(vs4 - bf2f(hb));
        hb = f2bf_rne(vs5); h8[5] = (short)hb; l8[5] = (short)f2bf_rne(vs5 - bf2f(hb));
        hb = f2bf_rne(vs6); h8[6] = (short)hb; l8[6] = (short)f2bf_rne(vs6 - bf2f(hb));
        hb = f2bf_rne(vs7); h8[7] = (short)hb; l8[7] = (short)f2bf_rne(vs7 - bf2f(hb));
        Ahi[kb] = h8; Alo[kb] = l8;
    }

    float asr[8], adr[8];
#pragma unroll
    for (int ct = 0; ct < 8; ++ct) {
        asr[ct] = a_src[ct * 16 + li];
        adr[ct] = a_dst[ct * 16 + li];
    }

    __syncthreads();

    f32x4 acc[8];
#pragma unroll
    for (int ct = 0; ct < 8; ++ct) acc[ct] = (f32x4){0.f, 0.f, 0.f, 0.f};

#pragma unroll
    for (int kb = 0; kb < 4; ++kb) {
#pragma unroll
        for (int ct = 0; ct < 8; ++ct) {
            bf16x8 bh = *reinterpret_cast<const bf16x8*>(&whi[((kb * 8 + ct) * 64 + lane) * 8]);
            bf16x8 bl = *reinterpret_cast<const bf16x8*>(&wlo[((kb * 8 + ct) * 64 + lane) * 8]);
            acc[ct] = __builtin_amdgcn_mfma_f32_16x16x32_bf16(Alo[kb], bh, acc[ct], 0, 0, 0);
            acc[ct] = __builtin_amdgcn_mfma_f32_16x16x32_bf16(Ahi[kb], bl, acc[ct], 0, 0, 0);
            acc[ct] = __builtin_amdgcn_mfma_f32_16x16x32_bf16(Ahi[kb], bh, acc[ct], 0, 0, 0);
        }
    }

#pragma unroll
    for (int q = 0; q < 4; ++q) {
        int n = rowbase + g * 4 + q;
        bool valid = (n < N);
        float p0s = 0.f, p1s = 0.f, p0d = 0.f, p1d = 0.f;
#pragma unroll
        for (int ct = 0; ct < 8; ++ct) {
            float h = acc[ct][q];
            if (valid) h1q[(long)n * HC1 + ct * 16 + li] = f2fp8(h);
            if (ct < 4) { p0s = fmaf(h, asr[ct], p0s); p0d = fmaf(h, adr[ct], p0d); }
            else        { p1s = fmaf(h, asr[ct], p1s); p1d = fmaf(h, adr[ct], p1d); }
        }
#pragma unroll
        for (int off = 8; off >= 1; off >>= 1) {
            p0s += __shfl_xor(p0s, off, 16);
            p1s += __shfl_xor(p1s, off, 16);
            p0d += __shfl_xor(p0d, off, 16);
            p1d += __shfl_xor(p1d, off, 16);
        }
        if (valid && li == 0) {
            as1[n * 2 + 0] = p0s; as1[n * 2 + 1] = p1s;
            ad1[n * 2 + 0] = p0d; ad1[n * 2 + 1] = p1d;
        }
    }
}

// ---------------------------------------------------------------------------
// FUSED CSR-build kernels: first nb_csr blocks do the CSR phase, remaining
// blocks run a gemm1 slice. tmp packed: (src<<8)|(dst&255), src < 2^24.
// ---------------------------------------------------------------------------
__global__ __launch_bounds__(256)
void f_bcnt(const int* __restrict__ ei, int* __restrict__ blockhist, int E, int NB,
            const float* __restrict__ x, const float* __restrict__ W1,
            const float* __restrict__ a_src, const float* __restrict__ a_dst,
            unsigned char* __restrict__ h1q, float* __restrict__ as1,
            float* __restrict__ ad1, int N, int nb_csr, int gemm_base) {
    __shared__ float4 smem[4096];   // 64 KB shared scratch
    int tid = threadIdx.x;
    if ((int)blockIdx.x >= nb_csr) {
        gemm1_body(x, W1, a_src, a_dst, h1q, as1, ad1, N,
                   gemm_base + blockIdx.x - nb_csr, smem);
        return;
    }
    int* h = (int*)smem;
    h[tid] = 0;
    __syncthreads();
    int base = blockIdx.x * EPB;
#pragma unroll
    for (int j = 0; j < EPB / 256; ++j) {
        int e = base + j * 256 + tid;
        if (e < E) atomicAdd(&h[ei[E + e] >> 8], 1);
    }
    __syncthreads();
    if (tid < NB) blockhist[blockIdx.x * NB + tid] = h[tid];
}

__global__ __launch_bounds__(256)
void f_colscan(int* __restrict__ blockhist, int* __restrict__ colsum, int EB, int NB,
               const float* __restrict__ x, const float* __restrict__ W1,
               const float* __restrict__ a_src, const float* __restrict__ a_dst,
               unsigned char* __restrict__ h1q, float* __restrict__ as1,
               float* __restrict__ ad1, int N, int nb_csr, int gemm_base) {
    __shared__ float4 smem[4096];
    int b = threadIdx.x;
    if ((int)blockIdx.x >= nb_csr) {
        gemm1_body(x, W1, a_src, a_dst, h1q, as1, ad1, N,
                   gemm_base + blockIdx.x - nb_csr, smem);
        return;
    }
    int* lds = (int*)smem;
    int t = blockIdx.x;       // bucket (column)
    int v = (b < EB) ? blockhist[b * NB + t] : 0;
    lds[b] = v;
    __syncthreads();
    for (int off = 1; off < 256; off <<= 1) {
        int u = (b >= off) ? lds[b - off] : 0;
        __syncthreads();
        lds[b] += u;
        __syncthreads();
    }
    if (b < EB) blockhist[b * NB + t] = lds[b] - v;   // excl offset within bucket
    if (b == 255) colsum[t] = lds[255];
}

// 1 block: exclusive scan of colsum -> bucket_base; + W2 prep.
__global__ __launch_bounds__(256)
void bscan2_kernel(const int* __restrict__ colsum, int* __restrict__ bucket_base,
                   int NB, const float* __restrict__ W2,
                   const float* __restrict__ a_src2, const float* __restrict__ a_dst2,
                   float* __restrict__ w2T, float* __restrict__ w2s,
                   float* __restrict__ w2d) {
    __shared__ int lds[256];
    int t = threadIdx.x;
    int v = (t < NB) ? colsum[t] : 0;
    lds[t] = v;
    __syncthreads();
    for (int off = 1; off < 256; off <<= 1) {
        int u = (t >= off) ? lds[t - off] : 0;
        __syncthreads();
        lds[t] += u;
        __syncthreads();
    }
    if (t < NB) bucket_base[t] = lds[t] - v;
    if (t == 255) bucket_base[NB] = lds[255];   // == E

    if (t < FIN) {
        float s = 0.f, d = 0.f;
#pragma unroll
        for (int c = 0; c < NCLS; ++c) {
            float w = W2[t * NCLS + c];
            w2T[c * FIN + t] = w;
            s = fmaf(w, a_src2[c], s);
            d = fmaf(w, a_dst2[c], d);
        }
        w2s[t] = s; w2d[t] = d;
    }
}

__global__ __launch_bounds__(256)
void f_binA(const int* __restrict__ ei, const int* __restrict__ blockhist,
            const int* __restrict__ bucket_base, int* __restrict__ tmp,
            int E, int NB,
            const float* __restrict__ x, const float* __restrict__ W1,
            const float* __restrict__ a_src, const float* __restrict__ a_dst,
            unsigned char* __restrict__ h1q, float* __restrict__ as1,
            float* __restrict__ ad1, int N, int nb_csr, int gemm_base) {
    __shared__ float4 smem[4096];
    int tid = threadIdx.x;
    if ((int)blockIdx.x >= nb_csr) {
        gemm1_body(x, W1, a_src, a_dst, h1q, as1, ad1, N,
                   gemm_base + blockIdx.x - nb_csr, smem);
        return;
    }
    int* h  = (int*)smem;        // local cursors [256]
    int* bb = h + 256;           // global base per bucket [256]
    h[tid] = 0;
    if (tid < NB) bb[tid] = blockhist[blockIdx.x * NB + tid] + bucket_base[tid];
    __syncthreads();
    int base = blockIdx.x * EPB;
#pragma unroll
    for (int j = 0; j < EPB / 256; ++j) {
        int e = base + j * 256 + tid;
        if (e < E) {
            int s = ei[e], d = ei[E + e];
            int b = d >> 8;
            int r = atomicAdd(&h[b], 1);
            tmp[bb[b] + r] = (s << 8) | (d & 255);   // packed
        }
    }
}

__global__ __launch_bounds__(256)
void f_binB(const int* __restrict__ tmp, const int* __restrict__ bucket_base,
            int* __restrict__ csr, int* __restrict__ eoffs, int E, int N,
            const float* __restrict__ x, const float* __restrict__ W1,
            const float* __restrict__ a_src, const float* __restrict__ a_dst,
            unsigned char* __restrict__ h1q, float* __restrict__ as1,
            float* __restrict__ ad1, int nb_csr, int gemm_base) {
    __shared__ float4 smem[4096];
    int t = threadIdx.x;
    if ((int)blockIdx.x >= nb_csr) {
        gemm1_body(x, W1, a_src, a_dst, h1q, as1, ad1, N,
                   gemm_base + blockIdx.x - nb_csr, smem);
        return;
    }
    int* cnt = (int*)smem;       // [256]
    int* lds = cnt + 256;        // [256]
    int* cur = cnt + 512;        // [256]
    int b = blockIdx.x;
    int lo = bucket_base[b], hi = bucket_base[b + 1];
    cnt[t] = 0;
    __syncthreads();
    for (int i = lo + t; i < hi; i += 256)
        atomicAdd(&cnt[tmp[i] & 255], 1);
    __syncthreads();
    int v = cnt[t];
    lds[t] = v;
    __syncthreads();
    for (int off = 1; off < 256; off <<= 1) {
        int u = (t >= off) ? lds[t - off] : 0;
        __syncthreads();
        lds[t] += u;
        __syncthreads();
    }
    int excl = lds[t] - v;
    int node = b * 256 + t;
    if (node < N) eoffs[node] = lo + excl;
    if (b == 0 && t == 0) eoffs[N] = E;
    cur[t] = lo + excl;
    __syncthreads();
    for (int i = lo + t; i < hi; i += 256) {
        int e = tmp[i];
        int p = atomicAdd(&cur[e & 255], 1);
        csr[p] = ((unsigned int)e) >> 8;     // src
    }
}

// ---------------------------------------------------------------------------
// Layer 1 FUSED gather+softmax+ELU+GEMM2+alpha2 over fp8 h1 rows (128 B).
// 32 lanes/node, 8 nodes per 256-block; each lane loads 4 B = 4 fp8 (cols
// 4l..4l+3), HW-decoded via v_cvt_pk_f32_fp8. Single edge pass, no
// max-subtraction; class-fold butterfly epilogue.
// ---------------------------------------------------------------------------
__global__ __launch_bounds__(256)
void fgather1(const int* __restrict__ eoffs, const int* __restrict__ csr,
              const float* __restrict__ as_arr, const float* __restrict__ ad_arr,
              const unsigned char* __restrict__ h1q, const float* __restrict__ b1,
              const float* __restrict__ w2T, const float* __restrict__ w2s,
              const float* __restrict__ w2d,
              float* __restrict__ zout, float* __restrict__ as2,
              float* __restrict__ ad2, int N) {
    int tid = threadIdx.x;
    int g = tid >> 5;                // 0..7 node-group in block (32-lane aligned)
    int l = tid & 31;                // lane in group: cols 4l..4l+3
    int n = blockIdx.x * 8 + g;
    if (n >= N) return;
    int head = l >> 4;
    int s0 = eoffs[n], s1 = eoffs[n + 1];

    float ad0 = ad_arr[2 * n], ad1v = ad_arr[2 * n + 1];
    float2 aself = *reinterpret_cast<const float2*>(&as_arr[2 * n]);
    float vs0 = aself.x + ad0;  vs0 = (vs0 >= 0.f) ? vs0 : NEG_SLOPE * vs0;
    float vs1 = aself.y + ad1v; vs1 = (vs1 >= 0.f) ? vs1 : NEG_SLOPE * vs1;
    float adn = head ? ad1v : ad0;

    float ps = __expf(head ? vs1 : vs0);
    unsigned int us = *reinterpret_cast<const unsigned int*>(&h1q[((long)n << 7) + 4 * l]);
    f32x2 slo = __builtin_amdgcn_cvt_pk_f32_fp8(us, false);
    f32x2 shi = __builtin_amdgcn_cvt_pk_f32_fp8(us, true);
    float4 acc;
    acc.x = slo[0] * ps; acc.y = slo[1] * ps;
    acc.z = shi[0] * ps; acc.w = shi[1] * ps;
    float den = ps;

    int i = s0;
    for (; i + 8 <= s1; i += 8) {
        int se[8];
#pragma unroll
        for (int j = 0; j < 8; ++j) se[j] = csr[i + j];
        float av[8];
#pragma unroll
        for (int j = 0; j < 8; ++j) av[j] = as_arr[2 * se[j] + head];
        unsigned int u[8];
#pragma unroll
        for (int j = 0; j < 8; ++j)
            u[j] = *reinterpret_cast<const unsigned int*>(&h1q[((long)se[j] << 7) + 4 * l]);
        float w[8];
#pragma unroll
        for (int j = 0; j < 8; ++j) {
            float v = av[j] + adn; v = (v >= 0.f) ? v : NEG_SLOPE * v;
            w[j] = __expf(v);
            den += w[j];
        }
#pragma unroll
        for (int j = 0; j < 8; ++j) {
            f32x2 lo = __builtin_amdgcn_cvt_pk_f32_fp8(u[j], false);
            f32x2 hi = __builtin_amdgcn_cvt_pk_f32_fp8(u[j], true);
            acc.x = fmaf(lo[0], w[j], acc.x);
            acc.y = fmaf(lo[1], w[j], acc.y);
            acc.z = fmaf(hi[0], w[j], acc.z);
            acc.w = fmaf(hi[1], w[j], acc.w);
        }
    }
    for (; i < s1; ++i) {
        int s = csr[i];
        float av = as_arr[2 * s + head];
        unsigned int u = *reinterpret_cast<const unsigned int*>(&h1q[((long)s << 7) + 4 * l]);
        float v = av + adn; v = (v >= 0.f) ? v : NEG_SLOPE * v;
        float w = __expf(v);
        den += w;
        f32x2 lo = __builtin_amdgcn_cvt_pk_f32_fp8(u, false);
        f32x2 hi = __builtin_amdgcn_cvt_pk_f32_fp8(u, true);
        acc.x = fmaf(lo[0], w, acc.x);
        acc.y = fmaf(lo[1], w, acc.y);
        acc.z = fmaf(hi[0], w, acc.z);
        acc.w = fmaf(hi[1], w, acc.w);
    }
    float r = 1.f / (den + 1e-16f);
    int col = 4 * l;
    float4 bb = *reinterpret_cast<const float4*>(&b1[col]);
    float4 o;
    o.x = acc.x * r + bb.x; o.y = acc.y * r + bb.y;
    o.z = acc.z * r + bb.z; o.w = acc.w * r + bb.w;
    o.x = (o.x > 0.f) ? o.x : expm1f(o.x);
    o.y = (o.y > 0.f) ? o.y : expm1f(o.y);
    o.z = (o.z > 0.f) ? o.z : expm1f(o.z);
    o.w = (o.w > 0.f) ? o.w : expm1f(o.w);

    // as2/ad2 = h2 . (W2 @ a_src2), h2 . (W2 @ a_dst2)  -- 10 shfl
    float4 ws4 = *reinterpret_cast<const float4*>(&w2s[col]);
    float4 wd4 = *reinterpret_cast<const float4*>(&w2d[col]);
    float sa2 = o.x * ws4.x + o.y * ws4.y + o.z * ws4.z + o.w * ws4.w;
    float da2 = o.x * wd4.x + o.y * wd4.y + o.z * wd4.z + o.w * wd4.w;
#pragma unroll
    for (int off = 16; off >= 1; off >>= 1) {
        sa2 += __shfl_xor(sa2, off, 32);
        da2 += __shfl_xor(da2, off, 32);
    }
    if (l == 0) { as2[n] = sa2; ad2[n] = da2; }

    // z = h2 @ W2 via class-fold butterfly (16 shfl total).
    float zp[NCLS];
#pragma unroll
    for (int c = 0; c < NCLS; ++c) {
        float4 w4 = *reinterpret_cast<const float4*>(&w2T[c * FIN + col]);
        zp[c] = o.x * w4.x + o.y * w4.y + o.z * w4.z + o.w * w4.w;
    }
    int bsel = (l >> 4) & 1;
    float z8[8];
#pragma unroll
    for (int j = 0; j < 8; ++j) {
        float send = bsel ? zp[j] : zp[j + 8];
        float keep = bsel ? zp[j + 8] : zp[j];
        z8[j] = keep + __shfl_xor(send, 16, 32);
    }
    bsel = (l >> 3) & 1;
    float z4v[4];
#pragma unroll
    for (int j = 0; j < 4; ++j) {
        float send = bsel ? z8[j] : z8[j + 4];
        float keep = bsel ? z8[j + 4] : z8[j];
        z4v[j] = keep + __shfl_xor(send, 8, 32);
    }
    bsel = (l >> 2) & 1;
    float z2v[2];
#pragma unroll
    for (int j = 0; j < 2; ++j) {
        float send = bsel ? z4v[j] : z4v[j + 2];
        float keep = bsel ? z4v[j + 2] : z4v[j];
        z2v[j] = keep + __shfl_xor(send, 4, 32);
    }
    bsel = (l >> 1) & 1;
    float z1v;
    {
        float send = bsel ? z2v[0] : z2v[1];
        float keep = bsel ? z2v[1] : z2v[0];
        z1v = keep + __shfl_xor(send, 2, 32);
    }
    z1v += __shfl_xor(z1v, 1, 32);
    if (!(l & 1)) zout[(long)n * NCLS + ((l >> 1) & 15)] = z1v;
}

// ---------------------------------------------------------------------------
// Layer 2 FUSED gather+softmax + bias + log_softmax (unchanged, z fp32).
// ---------------------------------------------------------------------------
__global__ __launch_bounds__(256)
void fgather2(const int* __restrict__ eoffs, const int* __restrict__ csr,
              const float* __restrict__ as2, const float* __restrict__ ad2,
              const float* __restrict__ z, const float* __restrict__ b2,
              float* __restrict__ out, int N) {
    int g = threadIdx.x >> 4;
    int l = threadIdx.x & 15;
    int n = blockIdx.x * 16 + g;
    if (n >= N) return;
    int s0 = eoffs[n], s1 = eoffs[n + 1];
    float adn = ad2[n];
    float vs = as2[n] + adn; vs = (vs >= 0.f) ? vs : NEG_SLOPE * vs;

    float ps = __expf(vs);
    float acc = ps * z[(long)n * NCLS + l];
    float den = ps;
    int i = s0;
    for (; i + 4 <= s1; i += 4) {
        int sa = csr[i], sb = csr[i + 1], sc = csr[i + 2], sd = csr[i + 3];
        float aa = as2[sa], ab = as2[sb], ac = as2[sc], ad = as2[sd];
        float za = z[sa * NCLS + l];
        float zb = z[sb * NCLS + l];
        float zc = z[sc * NCLS + l];
        float zd = z[sd * NCLS + l];
        float va = aa + adn; va = (va >= 0.f) ? va : NEG_SLOPE * va;
        float vb = ab + adn; vb = (vb >= 0.f) ? vb : NEG_SLOPE * vb;
        float vc = ac + adn; vc = (vc >= 0.f) ? vc : NEG_SLOPE * vc;
        float vd = ad + adn; vd = (vd >= 0.f) ? vd : NEG_SLOPE * vd;
        float pa = __expf(va);
        float pb = __expf(vb);
        float pc = __expf(vc);
        float pd = __expf(vd);
        den += pa + pb + pc + pd;
        acc = fmaf(za, pa, acc);
        acc = fmaf(zb, pb, acc);
        acc = fmaf(zc, pc, acc);
        acc = fmaf(zd, pd, acc);
    }
    for (; i < s1; ++i) {
        int s = csr[i];
        float v = as2[s] + adn; v = (v >= 0.f) ? v : NEG_SLOPE * v;
        float p = __expf(v);
        den += p;
        acc = fmaf(z[s * NCLS + l], p, acc);
    }

    float o = acc / (den + 1e-16f) + b2[l];

    float mx = o;
#pragma unroll
    for (int off = 8; off >= 1; off >>= 1) mx = fmaxf(mx, __shfl_xor(mx, off, 16));
    float ex = __expf(o - mx);
    float sum = ex;
#pragma unroll
    for (int off = 8; off >= 1; off >>= 1) sum += __shfl_xor(sum, off, 16);
    out[(long)n * NCLS + l] = o - mx - __logf(sum);
}

// ---------------------------------------------------------------------------
extern "C" void kernel_launch(void* const* d_in, const int* in_sizes, int n_in,
                              void* d_out, int out_size, void* d_ws, size_t ws_size,
                              hipStream_t stream) {
    const float* x        = (const float*)d_in[0];
    const int*   ei       = (const int*)  d_in[1];
    // d_in[2] = edge_attr (unused by reference)
    const float* W1       = (const float*)d_in[3];
    const float* att_src1 = (const float*)d_in[4];
    const float* att_dst1 = (const float*)d_in[5];
    const float* b1       = (const float*)d_in[6];
    const float* W2       = (const float*)d_in[7];
    const float* att_src2 = (const float*)d_in[8];
    const float* att_dst2 = (const float*)d_in[9];
    const float* b2       = (const float*)d_in[10];
    float* out = (float*)d_out;

    const int N = in_sizes[0] / FIN;        // 50000
    const int E = in_sizes[1] / 2;          // 800000
    const int NB = (N + 255) >> 8;          // 196 buckets
    const int EB = (E + EPB - 1) / EPB;     // 196 edge blocks (<=256)
    const int GB = (N + 63) / 64;           // 782 gemm1 blocks

    // gemm1 block slices fused into the 4 parallel CSR kernels
    int q = GB / 4, rr = GB % 4;
    int g0 = q + (rr > 0 ? 1 : 0);
    int g1 = q + (rr > 1 ? 1 : 0);
    int g2 = q + (rr > 2 ? 1 : 0);
    int g3 = q;
    int b0 = 0, b1o = g0, b2o = g0 + g1, b3o = g0 + g1 + g2;

    // Workspace layout (bytes)
    char* ws = (char*)d_ws;
    size_t off = 0;
    auto alloc = [&](size_t bytes) { char* p = ws + off; off += (bytes + 255) & ~(size_t)255; return p; };
    int*    blockhist     = (int*)  alloc((size_t)EB * NB * 4);
    int*    colsum        = (int*)  alloc((size_t)NB * 4);
    int*    bucket_base   = (int*)  alloc((size_t)(NB + 1) * 4);
    int*    tmp           = (int*)  alloc((size_t)E * 4);    // packed (src<<8)|dst&255
    int*    csr           = (int*)  alloc((size_t)E * 4);
    int*    eoffs         = (int*)  alloc((size_t)(N + 1) * 4);
    unsigned char* h1q    = (unsigned char*)alloc((size_t)N * HC1);  // fp8 e4m3
    float*  z             = (float*) alloc((size_t)N * NCLS * 4);
    float*  as1           = (float*) alloc((size_t)N * 2 * 4);
    float*  ad1           = (float*) alloc((size_t)N * 2 * 4);
    float*  as2           = (float*) alloc((size_t)N * 4);
    float*  ad2           = (float*) alloc((size_t)N * 4);
    float*  w2T           = (float*) alloc((size_t)NCLS * FIN * 4);
    float*  w2s           = (float*) alloc((size_t)FIN * 4);
    float*  w2d           = (float*) alloc((size_t)FIN * 4);
    (void)ws_size;

    f_bcnt<<<EB + g0, 256, 0, stream>>>(ei, blockhist, E, NB,
        x, W1, att_src1, att_dst1, h1q, as1, ad1, N, EB, b0);
    f_colscan<<<NB + g1, 256, 0, stream>>>(blockhist, colsum, EB, NB,
        x, W1, att_src1, att_dst1, h1q, as1, ad1, N, NB, b1o);
    bscan2_kernel<<<1, 256, 0, stream>>>(colsum, bucket_base, NB,
                                         W2, att_src2, att_dst2, w2T, w2s, w2d);
    f_binA<<<EB + g2, 256, 0, stream>>>(ei, blockhist, bucket_base, tmp, E, NB,
        x, W1, att_src1, att_dst1, h1q, as1, ad1, N, EB, b2o);
    f_binB<<<NB + g3, 256, 0, stream>>>(tmp, bucket_base, csr, eoffs, E, N,
        x, W1, att_src1, att_dst1, h1q, as1, ad1, NB, b3o);

    fgather1<<<(N + 7) / 8, 256, 0, stream>>>(
        eoffs, csr, as1, ad1, h1q, b1, w2T, w2s, w2d, z, as2, ad2, N);
    fgather2<<<(N + 15) / 16, 256, 0, stream>>>(eoffs, csr, as2, ad2, z, b2, out, N);
}

// Round 19
// 96.288 us; speedup vs baseline: 1.1693x; 1.0574x over previous
//
#include <hip/hip_runtime.h>
#include <math.h>

// Problem constants (match reference)
#define FIN   128
#define HC1   128   // H*C for layer 1
#define NCLS  16
#define NEG_SLOPE 0.2f

typedef __attribute__((ext_vector_type(8))) short bf16x8;
typedef __attribute__((ext_vector_type(4))) float f32x4;
typedef __attribute__((ext_vector_type(2))) float f32x2;

__device__ __forceinline__ unsigned short f2bf_rne(float f) {
    unsigned int u = __float_as_uint(f);
    unsigned int r = u + 0x7FFFu + ((u >> 16) & 1u);
    return (unsigned short)(r >> 16);
}
__device__ __forceinline__ float bf2f(unsigned short h) {
    return __uint_as_float(((unsigned int)h) << 16);
}

// fp8 e4m3 encode via HW converter (round-trips with the decode below).
__device__ __forceinline__ unsigned char f2fp8(float v) {
    int p = __builtin_amdgcn_cvt_pk_fp8_f32(v, v, 0, false);
    return (unsigned char)(p & 0xFF);
}

#define EPB 4096   // edges per block in bcnt/binA  (EB = ceil(E/EPB) must be <=256)

// ---------------------------------------------------------------------------
// gemm1 body (split-bf16 MFMA, h1=x@W1 -> fp8 e4m3, fused alpha1 reductions).
// ---------------------------------------------------------------------------
__device__ __forceinline__
void gemm1_body(const float* __restrict__ x, const float* __restrict__ W,
                const float* __restrict__ a_src, const float* __restrict__ a_dst,
                unsigned char* __restrict__ h1q, float* __restrict__ as1,
                float* __restrict__ ad1, int N, int bid, float4* smem) {
    unsigned short* whi = (unsigned short*)smem;          // 32 KB
    unsigned short* wlo = whi + FIN * HC1;                // 32 KB
    int tid = threadIdx.x;

#pragma unroll
    for (int i = 0; i < 64; ++i) {
        int idx = tid + i * 256;            // 0..16383, coalesced
        int k = idx >> 7, c = idx & 127;
        float v = W[idx];
        unsigned short hb = f2bf_rne(v);
        unsigned short lb = f2bf_rne(v - bf2f(hb));
        int kb = k >> 5, kk = k & 31;
        int g = kk >> 3, j = kk & 7;
        int ct = c >> 4, li = c & 15;
        int off = ((kb * 8 + ct) * 64 + g * 16 + li) * 8 + j;
        whi[off] = hb;
        wlo[off] = lb;
    }

    int wid = tid >> 6, lane = tid & 63;
    int li = lane & 15, g = lane >> 4;
    int rowbase = bid * 64 + wid * 16;

    int arow = rowbase + li;
    if (arow >= N) arow = N - 1;            // clamp; invalid rows never stored
    const float* xp = x + (long)arow * FIN + g * 8;
    bf16x8 Ahi[4], Alo[4];
#pragma unroll
    for (int kb = 0; kb < 4; ++kb) {
        float4 v0 = *reinterpret_cast<const float4*>(xp + kb * 32);
        float4 v1 = *reinterpret_cast<const float4*>(xp + kb * 32 + 4);
        float vs0 = v0.x, vs1 = v0.y, vs2 = v0.z, vs3 = v0.w;
        float vs4 = v1.x, vs5 = v1.y, vs6 = v1.z, vs7 = v1.w;
        bf16x8 h8, l8;
        unsigned short hb;
        hb = f2bf_rne(vs0); h8[0] = (short)hb; l8[0] = (short)f2bf_rne(vs0 - bf2f(hb));
        hb = f2bf_rne(vs1); h8[1] = (short)hb; l8[1] = (short)f2bf_rne(vs1 - bf2f(hb));
        hb = f2bf_rne(vs2); h8[2] = (short)hb; l8[2] = (short)f2bf_rne(vs2 - bf2f(hb));
        hb = f2bf_rne(vs3); h8[3] = (short)hb; l8[3] = (short)f2bf_rne(vs3 - bf2f(hb));
        hb = f2bf_rne(vs4); h8[4] = (short)hb; l8[4] = (short)f2bf_rne(vs4 - bf2f(hb));
        hb = f2bf_rne(vs5); h8[5] = (short)hb; l8[5] = (short)f2bf_rne(vs5 - bf2f(hb));
        hb = f2bf_rne(vs6); h8[6] = (short)hb; l8[6] = (short)f2bf_rne(vs6 - bf2f(hb));
        hb = f2bf_rne(vs7); h8[7] = (short)hb; l8[7] = (short)f2bf_rne(vs7 - bf2f(hb));
        Ahi[kb] = h8; Alo[kb] = l8;
    }

    float asr[8], adr[8];
#pragma unroll
    for (int ct = 0; ct < 8; ++ct) {
        asr[ct] = a_src[ct * 16 + li];
        adr[ct] = a_dst[ct * 16 + li];
    }

    __syncthreads();

    f32x4 acc[8];
#pragma unroll
    for (int ct = 0; ct < 8; ++ct) acc[ct] = (f32x4){0.f, 0.f, 0.f, 0.f};

#pragma unroll
    for (int kb = 0; kb < 4; ++kb) {
#pragma unroll
        for (int ct = 0; ct < 8; ++ct) {
            bf16x8 bh = *reinterpret_cast<const bf16x8*>(&whi[((kb * 8 + ct) * 64 + lane) * 8]);
            bf16x8 bl = *reinterpret_cast<const bf16x8*>(&wlo[((kb * 8 + ct) * 64 + lane) * 8]);
            acc[ct] = __builtin_amdgcn_mfma_f32_16x16x32_bf16(Alo[kb], bh, acc[ct], 0, 0, 0);
            acc[ct] = __builtin_amdgcn_mfma_f32_16x16x32_bf16(Ahi[kb], bl, acc[ct], 0, 0, 0);
            acc[ct] = __builtin_amdgcn_mfma_f32_16x16x32_bf16(Ahi[kb], bh, acc[ct], 0, 0, 0);
        }
    }

#pragma unroll
    for (int q = 0; q < 4; ++q) {
        int n = rowbase + g * 4 + q;
        bool valid = (n < N);
        float p0s = 0.f, p1s = 0.f, p0d = 0.f, p1d = 0.f;
#pragma unroll
        for (int ct = 0; ct < 8; ++ct) {
            float h = acc[ct][q];
            if (valid) h1q[(long)n * HC1 + ct * 16 + li] = f2fp8(h);
            if (ct < 4) { p0s = fmaf(h, asr[ct], p0s); p0d = fmaf(h, adr[ct], p0d); }
            else        { p1s = fmaf(h, asr[ct], p1s); p1d = fmaf(h, adr[ct], p1d); }
        }
#pragma unroll
        for (int off = 8; off >= 1; off >>= 1) {
            p0s += __shfl_xor(p0s, off, 16);
            p1s += __shfl_xor(p1s, off, 16);
            p0d += __shfl_xor(p0d, off, 16);
            p1d += __shfl_xor(p1d, off, 16);
        }
        if (valid && li == 0) {
            as1[n * 2 + 0] = p0s; as1[n * 2 + 1] = p1s;
            ad1[n * 2 + 0] = p0d; ad1[n * 2 + 1] = p1d;
        }
    }
}

// ---------------------------------------------------------------------------
// FUSED CSR-build kernels: first nb_csr blocks do the CSR phase, remaining
// blocks run a gemm1 slice. tmp packed: (src<<8)|(dst&255), src < 2^24.
// ---------------------------------------------------------------------------
__global__ __launch_bounds__(256)
void f_bcnt(const int* __restrict__ ei, int* __restrict__ blockhist, int E, int NB,
            const float* __restrict__ x, const float* __restrict__ W1,
            const float* __restrict__ a_src, const float* __restrict__ a_dst,
            unsigned char* __restrict__ h1q, float* __restrict__ as1,
            float* __restrict__ ad1, int N, int nb_csr, int gemm_base) {
    __shared__ float4 smem[4096];   // 64 KB shared scratch
    int tid = threadIdx.x;
    if ((int)blockIdx.x >= nb_csr) {
        gemm1_body(x, W1, a_src, a_dst, h1q, as1, ad1, N,
                   gemm_base + blockIdx.x - nb_csr, smem);
        return;
    }
    int* h = (int*)smem;
    h[tid] = 0;
    __syncthreads();
    int base = blockIdx.x * EPB;
#pragma unroll
    for (int j = 0; j < EPB / 256; ++j) {
        int e = base + j * 256 + tid;
        if (e < E) atomicAdd(&h[ei[E + e] >> 8], 1);
    }
    __syncthreads();
    if (tid < NB) blockhist[blockIdx.x * NB + tid] = h[tid];
}

__global__ __launch_bounds__(256)
void f_colscan(int* __restrict__ blockhist, int* __restrict__ colsum, int EB, int NB,
               const float* __restrict__ x, const float* __restrict__ W1,
               const float* __restrict__ a_src, const float* __restrict__ a_dst,
               unsigned char* __restrict__ h1q, float* __restrict__ as1,
               float* __restrict__ ad1, int N, int nb_csr, int gemm_base) {
    __shared__ float4 smem[4096];
    int b = threadIdx.x;
    if ((int)blockIdx.x >= nb_csr) {
        gemm1_body(x, W1, a_src, a_dst, h1q, as1, ad1, N,
                   gemm_base + blockIdx.x - nb_csr, smem);
        return;
    }
    int* lds = (int*)smem;
    int t = blockIdx.x;       // bucket (column)
    int v = (b < EB) ? blockhist[b * NB + t] : 0;
    lds[b] = v;
    __syncthreads();
    for (int off = 1; off < 256; off <<= 1) {
        int u = (b >= off) ? lds[b - off] : 0;
        __syncthreads();
        lds[b] += u;
        __syncthreads();
    }
    if (b < EB) blockhist[b * NB + t] = lds[b] - v;   // excl offset within bucket
    if (b == 255) colsum[t] = lds[255];
}

// 1 block: exclusive scan of colsum -> bucket_base; + W2 prep.
__global__ __launch_bounds__(256)
void bscan2_kernel(const int* __restrict__ colsum, int* __restrict__ bucket_base,
                   int NB, const float* __restrict__ W2,
                   const float* __restrict__ a_src2, const float* __restrict__ a_dst2,
                   float* __restrict__ w2T, float* __restrict__ w2s,
                   float* __restrict__ w2d) {
    __shared__ int lds[256];
    int t = threadIdx.x;
    int v = (t < NB) ? colsum[t] : 0;
    lds[t] = v;
    __syncthreads();
    for (int off = 1; off < 256; off <<= 1) {
        int u = (t >= off) ? lds[t - off] : 0;
        __syncthreads();
        lds[t] += u;
        __syncthreads();
    }
    if (t < NB) bucket_base[t] = lds[t] - v;
    if (t == 255) bucket_base[NB] = lds[255];   // == E

    if (t < FIN) {
        float s = 0.f, d = 0.f;
#pragma unroll
        for (int c = 0; c < NCLS; ++c) {
            float w = W2[t * NCLS + c];
            w2T[c * FIN + t] = w;
            s = fmaf(w, a_src2[c], s);
            d = fmaf(w, a_dst2[c], d);
        }
        w2s[t] = s; w2d[t] = d;
    }
}

__global__ __launch_bounds__(256)
void f_binA(const int* __restrict__ ei, const int* __restrict__ blockhist,
            const int* __restrict__ bucket_base, int* __restrict__ tmp,
            int E, int NB,
            const float* __restrict__ x, const float* __restrict__ W1,
            const float* __restrict__ a_src, const float* __restrict__ a_dst,
            unsigned char* __restrict__ h1q, float* __restrict__ as1,
            float* __restrict__ ad1, int N, int nb_csr, int gemm_base) {
    __shared__ float4 smem[4096];
    int tid = threadIdx.x;
    if ((int)blockIdx.x >= nb_csr) {
        gemm1_body(x, W1, a_src, a_dst, h1q, as1, ad1, N,
                   gemm_base + blockIdx.x - nb_csr, smem);
        return;
    }
    int* h  = (int*)smem;        // local cursors [256]
    int* bb = h + 256;           // global base per bucket [256]
    h[tid] = 0;
    if (tid < NB) bb[tid] = blockhist[blockIdx.x * NB + tid] + bucket_base[tid];
    __syncthreads();
    int base = blockIdx.x * EPB;
#pragma unroll
    for (int j = 0; j < EPB / 256; ++j) {
        int e = base + j * 256 + tid;
        if (e < E) {
            int s = ei[e], d = ei[E + e];
            int b = d >> 8;
            int r = atomicAdd(&h[b], 1);
            tmp[bb[b] + r] = (s << 8) | (d & 255);   // packed
        }
    }
}

__global__ __launch_bounds__(256)
void f_binB(const int* __restrict__ tmp, const int* __restrict__ bucket_base,
            int* __restrict__ csr, int* __restrict__ eoffs, int E, int N,
            const float* __restrict__ x, const float* __restrict__ W1,
            const float* __restrict__ a_src, const float* __restrict__ a_dst,
            unsigned char* __restrict__ h1q, float* __restrict__ as1,
            float* __restrict__ ad1, int nb_csr, int gemm_base) {
    __shared__ float4 smem[4096];
    int t = threadIdx.x;
    if ((int)blockIdx.x >= nb_csr) {
        gemm1_body(x, W1, a_src, a_dst, h1q, as1, ad1, N,
                   gemm_base + blockIdx.x - nb_csr, smem);
        return;
    }
    int* cnt = (int*)smem;       // [256]
    int* lds = cnt + 256;        // [256]
    int* cur = cnt + 512;        // [256]
    int b = blockIdx.x;
    int lo = bucket_base[b], hi = bucket_base[b + 1];
    cnt[t] = 0;
    __syncthreads();
    for (int i = lo + t; i < hi; i += 256)
        atomicAdd(&cnt[tmp[i] & 255], 1);
    __syncthreads();
    int v = cnt[t];
    lds[t] = v;
    __syncthreads();
    for (int off = 1; off < 256; off <<= 1) {
        int u = (t >= off) ? lds[t - off] : 0;
        __syncthreads();
        lds[t] += u;
        __syncthreads();
    }
    int excl = lds[t] - v;
    int node = b * 256 + t;
    if (node < N) eoffs[node] = lo + excl;
    if (b == 0 && t == 0) eoffs[N] = E;
    cur[t] = lo + excl;
    __syncthreads();
    for (int i = lo + t; i < hi; i += 256) {
        int e = tmp[i];
        int p = atomicAdd(&cur[e & 255], 1);
        csr[p] = ((unsigned int)e) >> 8;     // src
    }
}

// ---------------------------------------------------------------------------
// Layer 1 FUSED gather+softmax+ELU+GEMM2+alpha2 over fp8 h1 rows, v4:
// two-phase per 64-edge chunk. Phase A: each 16-lane head-group computes
// each edge score ONCE (2 exps/edge vs 32) and stages w + csr in LDS.
// Phase B: all 32 lanes gather with broadcast LDS reads. Same-wave LDS
// ordering -> barrier-free. 32 lanes/node, 8 nodes per 256-block.
// ---------------------------------------------------------------------------
#define CH 64   // edges per LDS chunk

__global__ __launch_bounds__(256)
void fgather1(const int* __restrict__ eoffs, const int* __restrict__ csr,
              const float* __restrict__ as_arr, const float* __restrict__ ad_arr,
              const unsigned char* __restrict__ h1q, const float* __restrict__ b1,
              const float* __restrict__ w2T, const float* __restrict__ w2s,
              const float* __restrict__ w2d,
              float* __restrict__ zout, float* __restrict__ as2,
              float* __restrict__ ad2, int N) {
    __shared__ float wbuf[8][2][CH];   // [group][head][edge]  4 KB
    __shared__ int   sbuf[8][CH];      // 2 KB
    int tid = threadIdx.x;
    int g = tid >> 5;                // 0..7 node-group in block (32-lane aligned)
    int l = tid & 31;                // lane in group: cols 4l..4l+3
    int n = blockIdx.x * 8 + g;
    if (n >= N) return;
    int head = l >> 4;
    int hl = l & 15;                 // lane within head-group
    int s0 = eoffs[n], s1 = eoffs[n + 1];

    float ad0 = ad_arr[2 * n], ad1v = ad_arr[2 * n + 1];
    float2 aself = *reinterpret_cast<const float2*>(&as_arr[2 * n]);
    float vs0 = aself.x + ad0;  vs0 = (vs0 >= 0.f) ? vs0 : NEG_SLOPE * vs0;
    float vs1 = aself.y + ad1v; vs1 = (vs1 >= 0.f) ? vs1 : NEG_SLOPE * vs1;
    float adn = head ? ad1v : ad0;

    float ps = __expf(head ? vs1 : vs0);
    unsigned int us = *reinterpret_cast<const unsigned int*>(&h1q[((long)n << 7) + 4 * l]);
    f32x2 slo = __builtin_amdgcn_cvt_pk_f32_fp8(us, false);
    f32x2 shi = __builtin_amdgcn_cvt_pk_f32_fp8(us, true);
    float4 acc;
    acc.x = slo[0] * ps; acc.y = slo[1] * ps;
    acc.z = shi[0] * ps; acc.w = shi[1] * ps;
    float denp = 0.f;   // per-lane partial denominator (reduced at end)

    for (int base = s0; base < s1; base += CH) {
        int cnt = min(CH, s1 - base);
        // Phase A: score each edge once per head; stage w and src in LDS.
        for (int j = hl; j < cnt; j += 16) {
            int s = csr[base + j];
            if (head == 0) sbuf[g][j] = s;
            float av = as_arr[2 * s + head];
            float v = av + adn; v = (v >= 0.f) ? v : NEG_SLOPE * v;
            float w = __expf(v);
            wbuf[g][head][j] = w;
            denp += w;
        }
        // Phase B: gather (broadcast LDS reads of w/s).
        int j = 0;
        for (; j + 4 <= cnt; j += 4) {
            int sa = sbuf[g][j],     sb = sbuf[g][j + 1];
            int sc = sbuf[g][j + 2], sd = sbuf[g][j + 3];
            float wa = wbuf[g][head][j],     wb = wbuf[g][head][j + 1];
            float wc = wbuf[g][head][j + 2], wd = wbuf[g][head][j + 3];
            unsigned int ua = *reinterpret_cast<const unsigned int*>(&h1q[((long)sa << 7) + 4 * l]);
            unsigned int ub = *reinterpret_cast<const unsigned int*>(&h1q[((long)sb << 7) + 4 * l]);
            unsigned int uc = *reinterpret_cast<const unsigned int*>(&h1q[((long)sc << 7) + 4 * l]);
            unsigned int ud = *reinterpret_cast<const unsigned int*>(&h1q[((long)sd << 7) + 4 * l]);
            f32x2 lo, hi;
            lo = __builtin_amdgcn_cvt_pk_f32_fp8(ua, false);
            hi = __builtin_amdgcn_cvt_pk_f32_fp8(ua, true);
            acc.x = fmaf(lo[0], wa, acc.x); acc.y = fmaf(lo[1], wa, acc.y);
            acc.z = fmaf(hi[0], wa, acc.z); acc.w = fmaf(hi[1], wa, acc.w);
            lo = __builtin_amdgcn_cvt_pk_f32_fp8(ub, false);
            hi = __builtin_amdgcn_cvt_pk_f32_fp8(ub, true);
            acc.x = fmaf(lo[0], wb, acc.x); acc.y = fmaf(lo[1], wb, acc.y);
            acc.z = fmaf(hi[0], wb, acc.z); acc.w = fmaf(hi[1], wb, acc.w);
            lo = __builtin_amdgcn_cvt_pk_f32_fp8(uc, false);
            hi = __builtin_amdgcn_cvt_pk_f32_fp8(uc, true);
            acc.x = fmaf(lo[0], wc, acc.x); acc.y = fmaf(lo[1], wc, acc.y);
            acc.z = fmaf(hi[0], wc, acc.z); acc.w = fmaf(hi[1], wc, acc.w);
            lo = __builtin_amdgcn_cvt_pk_f32_fp8(ud, false);
            hi = __builtin_amdgcn_cvt_pk_f32_fp8(ud, true);
            acc.x = fmaf(lo[0], wd, acc.x); acc.y = fmaf(lo[1], wd, acc.y);
            acc.z = fmaf(hi[0], wd, acc.z); acc.w = fmaf(hi[1], wd, acc.w);
        }
        for (; j < cnt; ++j) {
            int s = sbuf[g][j];
            float w = wbuf[g][head][j];
            unsigned int u = *reinterpret_cast<const unsigned int*>(&h1q[((long)s << 7) + 4 * l]);
            f32x2 lo = __builtin_amdgcn_cvt_pk_f32_fp8(u, false);
            f32x2 hi = __builtin_amdgcn_cvt_pk_f32_fp8(u, true);
            acc.x = fmaf(lo[0], w, acc.x); acc.y = fmaf(lo[1], w, acc.y);
            acc.z = fmaf(hi[0], w, acc.z); acc.w = fmaf(hi[1], w, acc.w);
        }
    }

    // Reduce partial denominators within each 16-lane head group; add self.
    float den = denp;
#pragma unroll
    for (int off = 8; off >= 1; off >>= 1) den += __shfl_xor(den, off, 16);
    den += ps;

    float r = 1.f / (den + 1e-16f);
    int col = 4 * l;
    float4 bb = *reinterpret_cast<const float4*>(&b1[col]);
    float4 o;
    o.x = acc.x * r + bb.x; o.y = acc.y * r + bb.y;
    o.z = acc.z * r + bb.z; o.w = acc.w * r + bb.w;
    o.x = (o.x > 0.f) ? o.x : expm1f(o.x);
    o.y = (o.y > 0.f) ? o.y : expm1f(o.y);
    o.z = (o.z > 0.f) ? o.z : expm1f(o.z);
    o.w = (o.w > 0.f) ? o.w : expm1f(o.w);

    // as2/ad2 = h2 . (W2 @ a_src2), h2 . (W2 @ a_dst2)  -- 10 shfl
    float4 ws4 = *reinterpret_cast<const float4*>(&w2s[col]);
    float4 wd4 = *reinterpret_cast<const float4*>(&w2d[col]);
    float sa2 = o.x * ws4.x + o.y * ws4.y + o.z * ws4.z + o.w * ws4.w;
    float da2 = o.x * wd4.x + o.y * wd4.y + o.z * wd4.z + o.w * wd4.w;
#pragma unroll
    for (int off = 16; off >= 1; off >>= 1) {
        sa2 += __shfl_xor(sa2, off, 32);
        da2 += __shfl_xor(da2, off, 32);
    }
    if (l == 0) { as2[n] = sa2; ad2[n] = da2; }

    // z = h2 @ W2 via class-fold butterfly (16 shfl total).
    float zp[NCLS];
#pragma unroll
    for (int c = 0; c < NCLS; ++c) {
        float4 w4 = *reinterpret_cast<const float4*>(&w2T[c * FIN + col]);
        zp[c] = o.x * w4.x + o.y * w4.y + o.z * w4.z + o.w * w4.w;
    }
    int bsel = (l >> 4) & 1;
    float z8[8];
#pragma unroll
    for (int j = 0; j < 8; ++j) {
        float send = bsel ? zp[j] : zp[j + 8];
        float keep = bsel ? zp[j + 8] : zp[j];
        z8[j] = keep + __shfl_xor(send, 16, 32);
    }
    bsel = (l >> 3) & 1;
    float z4v[4];
#pragma unroll
    for (int j = 0; j < 4; ++j) {
        float send = bsel ? z8[j] : z8[j + 4];
        float keep = bsel ? z8[j + 4] : z8[j];
        z4v[j] = keep + __shfl_xor(send, 8, 32);
    }
    bsel = (l >> 2) & 1;
    float z2v[2];
#pragma unroll
    for (int j = 0; j < 2; ++j) {
        float send = bsel ? z4v[j] : z4v[j + 2];
        float keep = bsel ? z4v[j + 2] : z4v[j];
        z2v[j] = keep + __shfl_xor(send, 4, 32);
    }
    bsel = (l >> 1) & 1;
    float z1v;
    {
        float send = bsel ? z2v[0] : z2v[1];
        float keep = bsel ? z2v[1] : z2v[0];
        z1v = keep + __shfl_xor(send, 2, 32);
    }
    z1v += __shfl_xor(z1v, 1, 32);
    if (!(l & 1)) zout[(long)n * NCLS + ((l >> 1) & 15)] = z1v;
}

// ---------------------------------------------------------------------------
// Layer 2 FUSED gather+softmax + bias + log_softmax (unchanged, z fp32).
// ---------------------------------------------------------------------------
__global__ __launch_bounds__(256)
void fgather2(const int* __restrict__ eoffs, const int* __restrict__ csr,
              const float* __restrict__ as2, const float* __restrict__ ad2,
              const float* __restrict__ z, const float* __restrict__ b2,
              float* __restrict__ out, int N) {
    int g = threadIdx.x >> 4;
    int l = threadIdx.x & 15;
    int n = blockIdx.x * 16 + g;
    if (n >= N) return;
    int s0 = eoffs[n], s1 = eoffs[n + 1];
    float adn = ad2[n];
    float vs = as2[n] + adn; vs = (vs >= 0.f) ? vs : NEG_SLOPE * vs;

    float ps = __expf(vs);
    float acc = ps * z[(long)n * NCLS + l];
    float den = ps;
    int i = s0;
    for (; i + 4 <= s1; i += 4) {
        int sa = csr[i], sb = csr[i + 1], sc = csr[i + 2], sd = csr[i + 3];
        float aa = as2[sa], ab = as2[sb], ac = as2[sc], ad = as2[sd];
        float za = z[sa * NCLS + l];
        float zb = z[sb * NCLS + l];
        float zc = z[sc * NCLS + l];
        float zd = z[sd * NCLS + l];
        float va = aa + adn; va = (va >= 0.f) ? va : NEG_SLOPE * va;
        float vb = ab + adn; vb = (vb >= 0.f) ? vb : NEG_SLOPE * vb;
        float vc = ac + adn; vc = (vc >= 0.f) ? vc : NEG_SLOPE * vc;
        float vd = ad + adn; vd = (vd >= 0.f) ? vd : NEG_SLOPE * vd;
        float pa = __expf(va);
        float pb = __expf(vb);
        float pc = __expf(vc);
        float pd = __expf(vd);
        den += pa + pb + pc + pd;
        acc = fmaf(za, pa, acc);
        acc = fmaf(zb, pb, acc);
        acc = fmaf(zc, pc, acc);
        acc = fmaf(zd, pd, acc);
    }
    for (; i < s1; ++i) {
        int s = csr[i];
        float v = as2[s] + adn; v = (v >= 0.f) ? v : NEG_SLOPE * v;
        float p = __expf(v);
        den += p;
        acc = fmaf(z[s * NCLS + l], p, acc);
    }

    float o = acc / (den + 1e-16f) + b2[l];

    float mx = o;
#pragma unroll
    for (int off = 8; off >= 1; off >>= 1) mx = fmaxf(mx, __shfl_xor(mx, off, 16));
    float ex = __expf(o - mx);
    float sum = ex;
#pragma unroll
    for (int off = 8; off >= 1; off >>= 1) sum += __shfl_xor(sum, off, 16);
    out[(long)n * NCLS + l] = o - mx - __logf(sum);
}

// ---------------------------------------------------------------------------
extern "C" void kernel_launch(void* const* d_in, const int* in_sizes, int n_in,
                              void* d_out, int out_size, void* d_ws, size_t ws_size,
                              hipStream_t stream) {
    const float* x        = (const float*)d_in[0];
    const int*   ei       = (const int*)  d_in[1];
    // d_in[2] = edge_attr (unused by reference)
    const float* W1       = (const float*)d_in[3];
    const float* att_src1 = (const float*)d_in[4];
    const float* att_dst1 = (const float*)d_in[5];
    const float* b1       = (const float*)d_in[6];
    const float* W2       = (const float*)d_in[7];
    const float* att_src2 = (const float*)d_in[8];
    const float* att_dst2 = (const float*)d_in[9];
    const float* b2       = (const float*)d_in[10];
    float* out = (float*)d_out;

    const int N = in_sizes[0] / FIN;        // 50000
    const int E = in_sizes[1] / 2;          // 800000
    const int NB = (N + 255) >> 8;          // 196 buckets
    const int EB = (E + EPB - 1) / EPB;     // 196 edge blocks (<=256)
    const int GB = (N + 63) / 64;           // 782 gemm1 blocks

    // gemm1 block slices fused into the 4 parallel CSR kernels
    int q = GB / 4, rr = GB % 4;
    int g0 = q + (rr > 0 ? 1 : 0);
    int g1 = q + (rr > 1 ? 1 : 0);
    int g2 = q + (rr > 2 ? 1 : 0);
    int g3 = q;
    int b0 = 0, b1o = g0, b2o = g0 + g1, b3o = g0 + g1 + g2;

    // Workspace layout (bytes)
    char* ws = (char*)d_ws;
    size_t off = 0;
    auto alloc = [&](size_t bytes) { char* p = ws + off; off += (bytes + 255) & ~(size_t)255; return p; };
    int*    blockhist     = (int*)  alloc((size_t)EB * NB * 4);
    int*    colsum        = (int*)  alloc((size_t)NB * 4);
    int*    bucket_base   = (int*)  alloc((size_t)(NB + 1) * 4);
    int*    tmp           = (int*)  alloc((size_t)E * 4);    // packed (src<<8)|dst&255
    int*    csr           = (int*)  alloc((size_t)E * 4);
    int*    eoffs         = (int*)  alloc((size_t)(N + 1) * 4);
    unsigned char* h1q    = (unsigned char*)alloc((size_t)N * HC1);  // fp8 e4m3
    float*  z             = (float*) alloc((size_t)N * NCLS * 4);
    float*  as1           = (float*) alloc((size_t)N * 2 * 4);
    float*  ad1           = (float*) alloc((size_t)N * 2 * 4);
    float*  as2           = (float*) alloc((size_t)N * 4);
    float*  ad2           = (float*) alloc((size_t)N * 4);
    float*  w2T           = (float*) alloc((size_t)NCLS * FIN * 4);
    float*  w2s           = (float*) alloc((size_t)FIN * 4);
    float*  w2d           = (float*) alloc((size_t)FIN * 4);
    (void)ws_size;

    f_bcnt<<<EB + g0, 256, 0, stream>>>(ei, blockhist, E, NB,
        x, W1, att_src1, att_dst1, h1q, as1, ad1, N, EB, b0);
    f_colscan<<<NB + g1, 256, 0, stream>>>(blockhist, colsum, EB, NB,
        x, W1, att_src1, att_dst1, h1q, as1, ad1, N, NB, b1o);
    bscan2_kernel<<<1, 256, 0, stream>>>(colsum, bucket_base, NB,
                                         W2, att_src2, att_dst2, w2T, w2s, w2d);
    f_binA<<<EB + g2, 256, 0, stream>>>(ei, blockhist, bucket_base, tmp, E, NB,
        x, W1, att_src1, att_dst1, h1q, as1, ad1, N, EB, b2o);
    f_binB<<<NB + g3, 256, 0, stream>>>(tmp, bucket_base, csr, eoffs, E, N,
        x, W1, att_src1, att_dst1, h1q, as1, ad1, NB, b3o);

    fgather1<<<(N + 7) / 8, 256, 0, stream>>>(
        eoffs, csr, as1, ad1, h1q, b1, w2T, w2s, w2d, z, as2, ad2, N);
    fgather2<<<(N + 15) / 16, 256, 0, stream>>>(eoffs, csr, as2, ad2, z, b2, out, N);
}

// Round 20
// 95.875 us; speedup vs baseline: 1.1743x; 1.0043x over previous
//
#include <hip/hip_runtime.h>
#include <math.h>

// Problem constants (match reference)
#define FIN   128
#define HC1   128   // H*C for layer 1
#define NCLS  16
#define NEG_SLOPE 0.2f

typedef __attribute__((ext_vector_type(8))) short bf16x8;
typedef __attribute__((ext_vector_type(4))) float f32x4;
typedef __attribute__((ext_vector_type(2))) float f32x2;

__device__ __forceinline__ unsigned short f2bf_rne(float f) {
    unsigned int u = __float_as_uint(f);
    unsigned int r = u + 0x7FFFu + ((u >> 16) & 1u);
    return (unsigned short)(r >> 16);
}
__device__ __forceinline__ float bf2f(unsigned short h) {
    return __uint_as_float(((unsigned int)h) << 16);
}

// fp8 e4m3 encode via HW converter (round-trips with the decode below).
__device__ __forceinline__ unsigned char f2fp8(float v) {
    int p = __builtin_amdgcn_cvt_pk_fp8_f32(v, v, 0, false);
    return (unsigned char)(p & 0xFF);
}

#define EPB 4096   // edges per block in bcnt/binA  (EB = ceil(E/EPB) must be <=256)

// ---------------------------------------------------------------------------
// gemm1 body (split-bf16 MFMA, h1=x@W1 -> fp8 e4m3, fused alpha1 reductions).
// ---------------------------------------------------------------------------
__device__ __forceinline__
void gemm1_body(const float* __restrict__ x, const float* __restrict__ W,
                const float* __restrict__ a_src, const float* __restrict__ a_dst,
                unsigned char* __restrict__ h1q, float* __restrict__ as1,
                float* __restrict__ ad1, int N, int bid, float4* smem) {
    unsigned short* whi = (unsigned short*)smem;          // 32 KB
    unsigned short* wlo = whi + FIN * HC1;                // 32 KB
    int tid = threadIdx.x;

#pragma unroll
    for (int i = 0; i < 64; ++i) {
        int idx = tid + i * 256;            // 0..16383, coalesced
        int k = idx >> 7, c = idx & 127;
        float v = W[idx];
        unsigned short hb = f2bf_rne(v);
        unsigned short lb = f2bf_rne(v - bf2f(hb));
        int kb = k >> 5, kk = k & 31;
        int g = kk >> 3, j = kk & 7;
        int ct = c >> 4, li = c & 15;
        int off = ((kb * 8 + ct) * 64 + g * 16 + li) * 8 + j;
        whi[off] = hb;
        wlo[off] = lb;
    }

    int wid = tid >> 6, lane = tid & 63;
    int li = lane & 15, g = lane >> 4;
    int rowbase = bid * 64 + wid * 16;

    int arow = rowbase + li;
    if (arow >= N) arow = N - 1;            // clamp; invalid rows never stored
    const float* xp = x + (long)arow * FIN + g * 8;
    bf16x8 Ahi[4], Alo[4];
#pragma unroll
    for (int kb = 0; kb < 4; ++kb) {
        float4 v0 = *reinterpret_cast<const float4*>(xp + kb * 32);
        float4 v1 = *reinterpret_cast<const float4*>(xp + kb * 32 + 4);
        float vs0 = v0.x, vs1 = v0.y, vs2 = v0.z, vs3 = v0.w;
        float vs4 = v1.x, vs5 = v1.y, vs6 = v1.z, vs7 = v1.w;
        bf16x8 h8, l8;
        unsigned short hb;
        hb = f2bf_rne(vs0); h8[0] = (short)hb; l8[0] = (short)f2bf_rne(vs0 - bf2f(hb));
        hb = f2bf_rne(vs1); h8[1] = (short)hb; l8[1] = (short)f2bf_rne(vs1 - bf2f(hb));
        hb = f2bf_rne(vs2); h8[2] = (short)hb; l8[2] = (short)f2bf_rne(vs2 - bf2f(hb));
        hb = f2bf_rne(vs3); h8[3] = (short)hb; l8[3] = (short)f2bf_rne(vs3 - bf2f(hb));
        hb = f2bf_rne(vs4); h8[4] = (short)hb; l8[4] = (short)f2bf_rne(vs4 - bf2f(hb));
        hb = f2bf_rne(vs5); h8[5] = (short)hb; l8[5] = (short)f2bf_rne(vs5 - bf2f(hb));
        hb = f2bf_rne(vs6); h8[6] = (short)hb; l8[6] = (short)f2bf_rne(vs6 - bf2f(hb));
        hb = f2bf_rne(vs7); h8[7] = (short)hb; l8[7] = (short)f2bf_rne(vs7 - bf2f(hb));
        Ahi[kb] = h8; Alo[kb] = l8;
    }

    float asr[8], adr[8];
#pragma unroll
    for (int ct = 0; ct < 8; ++ct) {
        asr[ct] = a_src[ct * 16 + li];
        adr[ct] = a_dst[ct * 16 + li];
    }

    __syncthreads();

    f32x4 acc[8];
#pragma unroll
    for (int ct = 0; ct < 8; ++ct) acc[ct] = (f32x4){0.f, 0.f, 0.f, 0.f};

#pragma unroll
    for (int kb = 0; kb < 4; ++kb) {
#pragma unroll
        for (int ct = 0; ct < 8; ++ct) {
            bf16x8 bh = *reinterpret_cast<const bf16x8*>(&whi[((kb * 8 + ct) * 64 + lane) * 8]);
            bf16x8 bl = *reinterpret_cast<const bf16x8*>(&wlo[((kb * 8 + ct) * 64 + lane) * 8]);
            acc[ct] = __builtin_amdgcn_mfma_f32_16x16x32_bf16(Alo[kb], bh, acc[ct], 0, 0, 0);
            acc[ct] = __builtin_amdgcn_mfma_f32_16x16x32_bf16(Ahi[kb], bl, acc[ct], 0, 0, 0);
            acc[ct] = __builtin_amdgcn_mfma_f32_16x16x32_bf16(Ahi[kb], bh, acc[ct], 0, 0, 0);
        }
    }

#pragma unroll
    for (int q = 0; q < 4; ++q) {
        int n = rowbase + g * 4 + q;
        bool valid = (n < N);
        float p0s = 0.f, p1s = 0.f, p0d = 0.f, p1d = 0.f;
#pragma unroll
        for (int ct = 0; ct < 8; ++ct) {
            float h = acc[ct][q];
            if (valid) h1q[(long)n * HC1 + ct * 16 + li] = f2fp8(h);
            if (ct < 4) { p0s = fmaf(h, asr[ct], p0s); p0d = fmaf(h, adr[ct], p0d); }
            else        { p1s = fmaf(h, asr[ct], p1s); p1d = fmaf(h, adr[ct], p1d); }
        }
#pragma unroll
        for (int off = 8; off >= 1; off >>= 1) {
            p0s += __shfl_xor(p0s, off, 16);
            p1s += __shfl_xor(p1s, off, 16);
            p0d += __shfl_xor(p0d, off, 16);
            p1d += __shfl_xor(p1d, off, 16);
        }
        if (valid && li == 0) {
            as1[n * 2 + 0] = p0s; as1[n * 2 + 1] = p1s;
            ad1[n * 2 + 0] = p0d; ad1[n * 2 + 1] = p1d;
        }
    }
}

// ---------------------------------------------------------------------------
// FUSED CSR-build kernels: first nb_csr blocks do the CSR phase, remaining
// blocks run a gemm1 slice. tmp packed: (src<<8)|(dst&255), src < 2^24.
// ---------------------------------------------------------------------------
__global__ __launch_bounds__(256)
void f_bcnt(const int* __restrict__ ei, int* __restrict__ blockhist, int E, int NB,
            const float* __restrict__ x, const float* __restrict__ W1,
            const float* __restrict__ a_src, const float* __restrict__ a_dst,
            unsigned char* __restrict__ h1q, float* __restrict__ as1,
            float* __restrict__ ad1, int N, int nb_csr, int gemm_base) {
    __shared__ float4 smem[4096];   // 64 KB shared scratch
    int tid = threadIdx.x;
    if ((int)blockIdx.x >= nb_csr) {
        gemm1_body(x, W1, a_src, a_dst, h1q, as1, ad1, N,
                   gemm_base + blockIdx.x - nb_csr, smem);
        return;
    }
    int* h = (int*)smem;
    h[tid] = 0;
    __syncthreads();
    int base = blockIdx.x * EPB;
#pragma unroll
    for (int j = 0; j < EPB / 256; ++j) {
        int e = base + j * 256 + tid;
        if (e < E) atomicAdd(&h[ei[E + e] >> 8], 1);
    }
    __syncthreads();
    if (tid < NB) blockhist[blockIdx.x * NB + tid] = h[tid];
}

__global__ __launch_bounds__(256)
void f_colscan(int* __restrict__ blockhist, int* __restrict__ colsum, int EB, int NB,
               const float* __restrict__ x, const float* __restrict__ W1,
               const float* __restrict__ a_src, const float* __restrict__ a_dst,
               unsigned char* __restrict__ h1q, float* __restrict__ as1,
               float* __restrict__ ad1, int N, int nb_csr, int gemm_base) {
    __shared__ float4 smem[4096];
    int b = threadIdx.x;
    if ((int)blockIdx.x >= nb_csr) {
        gemm1_body(x, W1, a_src, a_dst, h1q, as1, ad1, N,
                   gemm_base + blockIdx.x - nb_csr, smem);
        return;
    }
    int* lds = (int*)smem;
    int t = blockIdx.x;       // bucket (column)
    int v = (b < EB) ? blockhist[b * NB + t] : 0;
    lds[b] = v;
    __syncthreads();
    for (int off = 1; off < 256; off <<= 1) {
        int u = (b >= off) ? lds[b - off] : 0;
        __syncthreads();
        lds[b] += u;
        __syncthreads();
    }
    if (b < EB) blockhist[b * NB + t] = lds[b] - v;   // excl offset within bucket
    if (b == 255) colsum[t] = lds[255];
}

// 1 block: exclusive scan of colsum -> bucket_base; + W2 prep.
__global__ __launch_bounds__(256)
void bscan2_kernel(const int* __restrict__ colsum, int* __restrict__ bucket_base,
                   int NB, const float* __restrict__ W2,
                   const float* __restrict__ a_src2, const float* __restrict__ a_dst2,
                   float* __restrict__ w2T, float* __restrict__ w2s,
                   float* __restrict__ w2d) {
    __shared__ int lds[256];
    int t = threadIdx.x;
    int v = (t < NB) ? colsum[t] : 0;
    lds[t] = v;
    __syncthreads();
    for (int off = 1; off < 256; off <<= 1) {
        int u = (t >= off) ? lds[t - off] : 0;
        __syncthreads();
        lds[t] += u;
        __syncthreads();
    }
    if (t < NB) bucket_base[t] = lds[t] - v;
    if (t == 255) bucket_base[NB] = lds[255];   // == E

    if (t < FIN) {
        float s = 0.f, d = 0.f;
#pragma unroll
        for (int c = 0; c < NCLS; ++c) {
            float w = W2[t * NCLS + c];
            w2T[c * FIN + t] = w;
            s = fmaf(w, a_src2[c], s);
            d = fmaf(w, a_dst2[c], d);
        }
        w2s[t] = s; w2d[t] = d;
    }
}

__global__ __launch_bounds__(256)
void f_binA(const int* __restrict__ ei, const int* __restrict__ blockhist,
            const int* __restrict__ bucket_base, int* __restrict__ tmp,
            int E, int NB,
            const float* __restrict__ x, const float* __restrict__ W1,
            const float* __restrict__ a_src, const float* __restrict__ a_dst,
            unsigned char* __restrict__ h1q, float* __restrict__ as1,
            float* __restrict__ ad1, int N, int nb_csr, int gemm_base) {
    __shared__ float4 smem[4096];
    int tid = threadIdx.x;
    if ((int)blockIdx.x >= nb_csr) {
        gemm1_body(x, W1, a_src, a_dst, h1q, as1, ad1, N,
                   gemm_base + blockIdx.x - nb_csr, smem);
        return;
    }
    int* h  = (int*)smem;        // local cursors [256]
    int* bb = h + 256;           // global base per bucket [256]
    h[tid] = 0;
    if (tid < NB) bb[tid] = blockhist[blockIdx.x * NB + tid] + bucket_base[tid];
    __syncthreads();
    int base = blockIdx.x * EPB;
#pragma unroll
    for (int j = 0; j < EPB / 256; ++j) {
        int e = base + j * 256 + tid;
        if (e < E) {
            int s = ei[e], d = ei[E + e];
            int b = d >> 8;
            int r = atomicAdd(&h[b], 1);
            tmp[bb[b] + r] = (s << 8) | (d & 255);   // packed
        }
    }
}

__global__ __launch_bounds__(256)
void f_binB(const int* __restrict__ tmp, const int* __restrict__ bucket_base,
            int* __restrict__ csr, int* __restrict__ eoffs, int E, int N,
            const float* __restrict__ x, const float* __restrict__ W1,
            const float* __restrict__ a_src, const float* __restrict__ a_dst,
            unsigned char* __restrict__ h1q, float* __restrict__ as1,
            float* __restrict__ ad1, int nb_csr, int gemm_base) {
    __shared__ float4 smem[4096];
    int t = threadIdx.x;
    if ((int)blockIdx.x >= nb_csr) {
        gemm1_body(x, W1, a_src, a_dst, h1q, as1, ad1, N,
                   gemm_base + blockIdx.x - nb_csr, smem);
        return;
    }
    int* cnt = (int*)smem;       // [256]
    int* lds = cnt + 256;        // [256]
    int* cur = cnt + 512;        // [256]
    int b = blockIdx.x;
    int lo = bucket_base[b], hi = bucket_base[b + 1];
    cnt[t] = 0;
    __syncthreads();
    for (int i = lo + t; i < hi; i += 256)
        atomicAdd(&cnt[tmp[i] & 255], 1);
    __syncthreads();
    int v = cnt[t];
    lds[t] = v;
    __syncthreads();
    for (int off = 1; off < 256; off <<= 1) {
        int u = (t >= off) ? lds[t - off] : 0;
        __syncthreads();
        lds[t] += u;
        __syncthreads();
    }
    int excl = lds[t] - v;
    int node = b * 256 + t;
    if (node < N) eoffs[node] = lo + excl;
    if (b == 0 && t == 0) eoffs[N] = E;
    cur[t] = lo + excl;
    __syncthreads();
    for (int i = lo + t; i < hi; i += 256) {
        int e = tmp[i];
        int p = atomicAdd(&cur[e & 255], 1);
        csr[p] = ((unsigned int)e) >> 8;     // src
    }
}

// ---------------------------------------------------------------------------
// Layer 1 FUSED gather+softmax+ELU+GEMM2+alpha2 over fp8 h1 rows, v4:
// two-phase per 64-edge chunk (score dedup via LDS). Unchanged from R19.
// ---------------------------------------------------------------------------
#define CH 64   // edges per LDS chunk (fgather1)

__global__ __launch_bounds__(256)
void fgather1(const int* __restrict__ eoffs, const int* __restrict__ csr,
              const float* __restrict__ as_arr, const float* __restrict__ ad_arr,
              const unsigned char* __restrict__ h1q, const float* __restrict__ b1,
              const float* __restrict__ w2T, const float* __restrict__ w2s,
              const float* __restrict__ w2d,
              float* __restrict__ zout, float* __restrict__ as2,
              float* __restrict__ ad2, int N) {
    __shared__ float wbuf[8][2][CH];   // [group][head][edge]  4 KB
    __shared__ int   sbuf[8][CH];      // 2 KB
    int tid = threadIdx.x;
    int g = tid >> 5;                // 0..7 node-group in block (32-lane aligned)
    int l = tid & 31;                // lane in group: cols 4l..4l+3
    int n = blockIdx.x * 8 + g;
    if (n >= N) return;
    int head = l >> 4;
    int hl = l & 15;                 // lane within head-group
    int s0 = eoffs[n], s1 = eoffs[n + 1];

    float ad0 = ad_arr[2 * n], ad1v = ad_arr[2 * n + 1];
    float2 aself = *reinterpret_cast<const float2*>(&as_arr[2 * n]);
    float vs0 = aself.x + ad0;  vs0 = (vs0 >= 0.f) ? vs0 : NEG_SLOPE * vs0;
    float vs1 = aself.y + ad1v; vs1 = (vs1 >= 0.f) ? vs1 : NEG_SLOPE * vs1;
    float adn = head ? ad1v : ad0;

    float ps = __expf(head ? vs1 : vs0);
    unsigned int us = *reinterpret_cast<const unsigned int*>(&h1q[((long)n << 7) + 4 * l]);
    f32x2 slo = __builtin_amdgcn_cvt_pk_f32_fp8(us, false);
    f32x2 shi = __builtin_amdgcn_cvt_pk_f32_fp8(us, true);
    float4 acc;
    acc.x = slo[0] * ps; acc.y = slo[1] * ps;
    acc.z = shi[0] * ps; acc.w = shi[1] * ps;
    float denp = 0.f;   // per-lane partial denominator (reduced at end)

    for (int base = s0; base < s1; base += CH) {
        int cnt = min(CH, s1 - base);
        // Phase A: score each edge once per head; stage w and src in LDS.
        for (int j = hl; j < cnt; j += 16) {
            int s = csr[base + j];
            if (head == 0) sbuf[g][j] = s;
            float av = as_arr[2 * s + head];
            float v = av + adn; v = (v >= 0.f) ? v : NEG_SLOPE * v;
            float w = __expf(v);
            wbuf[g][head][j] = w;
            denp += w;
        }
        // Phase B: gather (broadcast LDS reads of w/s).
        int j = 0;
        for (; j + 4 <= cnt; j += 4) {
            int sa = sbuf[g][j],     sb = sbuf[g][j + 1];
            int sc = sbuf[g][j + 2], sd = sbuf[g][j + 3];
            float wa = wbuf[g][head][j],     wb = wbuf[g][head][j + 1];
            float wc = wbuf[g][head][j + 2], wd = wbuf[g][head][j + 3];
            unsigned int ua = *reinterpret_cast<const unsigned int*>(&h1q[((long)sa << 7) + 4 * l]);
            unsigned int ub = *reinterpret_cast<const unsigned int*>(&h1q[((long)sb << 7) + 4 * l]);
            unsigned int uc = *reinterpret_cast<const unsigned int*>(&h1q[((long)sc << 7) + 4 * l]);
            unsigned int ud = *reinterpret_cast<const unsigned int*>(&h1q[((long)sd << 7) + 4 * l]);
            f32x2 lo, hi;
            lo = __builtin_amdgcn_cvt_pk_f32_fp8(ua, false);
            hi = __builtin_amdgcn_cvt_pk_f32_fp8(ua, true);
            acc.x = fmaf(lo[0], wa, acc.x); acc.y = fmaf(lo[1], wa, acc.y);
            acc.z = fmaf(hi[0], wa, acc.z); acc.w = fmaf(hi[1], wa, acc.w);
            lo = __builtin_amdgcn_cvt_pk_f32_fp8(ub, false);
            hi = __builtin_amdgcn_cvt_pk_f32_fp8(ub, true);
            acc.x = fmaf(lo[0], wb, acc.x); acc.y = fmaf(lo[1], wb, acc.y);
            acc.z = fmaf(hi[0], wb, acc.z); acc.w = fmaf(hi[1], wb, acc.w);
            lo = __builtin_amdgcn_cvt_pk_f32_fp8(uc, false);
            hi = __builtin_amdgcn_cvt_pk_f32_fp8(uc, true);
            acc.x = fmaf(lo[0], wc, acc.x); acc.y = fmaf(lo[1], wc, acc.y);
            acc.z = fmaf(hi[0], wc, acc.z); acc.w = fmaf(hi[1], wc, acc.w);
            lo = __builtin_amdgcn_cvt_pk_f32_fp8(ud, false);
            hi = __builtin_amdgcn_cvt_pk_f32_fp8(ud, true);
            acc.x = fmaf(lo[0], wd, acc.x); acc.y = fmaf(lo[1], wd, acc.y);
            acc.z = fmaf(hi[0], wd, acc.z); acc.w = fmaf(hi[1], wd, acc.w);
        }
        for (; j < cnt; ++j) {
            int s = sbuf[g][j];
            float w = wbuf[g][head][j];
            unsigned int u = *reinterpret_cast<const unsigned int*>(&h1q[((long)s << 7) + 4 * l]);
            f32x2 lo = __builtin_amdgcn_cvt_pk_f32_fp8(u, false);
            f32x2 hi = __builtin_amdgcn_cvt_pk_f32_fp8(u, true);
            acc.x = fmaf(lo[0], w, acc.x); acc.y = fmaf(lo[1], w, acc.y);
            acc.z = fmaf(hi[0], w, acc.z); acc.w = fmaf(hi[1], w, acc.w);
        }
    }

    // Reduce partial denominators within each 16-lane head group; add self.
    float den = denp;
#pragma unroll
    for (int off = 8; off >= 1; off >>= 1) den += __shfl_xor(den, off, 16);
    den += ps;

    float r = 1.f / (den + 1e-16f);
    int col = 4 * l;
    float4 bb = *reinterpret_cast<const float4*>(&b1[col]);
    float4 o;
    o.x = acc.x * r + bb.x; o.y = acc.y * r + bb.y;
    o.z = acc.z * r + bb.z; o.w = acc.w * r + bb.w;
    o.x = (o.x > 0.f) ? o.x : expm1f(o.x);
    o.y = (o.y > 0.f) ? o.y : expm1f(o.y);
    o.z = (o.z > 0.f) ? o.z : expm1f(o.z);
    o.w = (o.w > 0.f) ? o.w : expm1f(o.w);

    // as2/ad2 = h2 . (W2 @ a_src2), h2 . (W2 @ a_dst2)  -- 10 shfl
    float4 ws4 = *reinterpret_cast<const float4*>(&w2s[col]);
    float4 wd4 = *reinterpret_cast<const float4*>(&w2d[col]);
    float sa2 = o.x * ws4.x + o.y * ws4.y + o.z * ws4.z + o.w * ws4.w;
    float da2 = o.x * wd4.x + o.y * wd4.y + o.z * wd4.z + o.w * wd4.w;
#pragma unroll
    for (int off = 16; off >= 1; off >>= 1) {
        sa2 += __shfl_xor(sa2, off, 32);
        da2 += __shfl_xor(da2, off, 32);
    }
    if (l == 0) { as2[n] = sa2; ad2[n] = da2; }

    // z = h2 @ W2 via class-fold butterfly (16 shfl total).
    float zp[NCLS];
#pragma unroll
    for (int c = 0; c < NCLS; ++c) {
        float4 w4 = *reinterpret_cast<const float4*>(&w2T[c * FIN + col]);
        zp[c] = o.x * w4.x + o.y * w4.y + o.z * w4.z + o.w * w4.w;
    }
    int bsel = (l >> 4) & 1;
    float z8[8];
#pragma unroll
    for (int j = 0; j < 8; ++j) {
        float send = bsel ? zp[j] : zp[j + 8];
        float keep = bsel ? zp[j + 8] : zp[j];
        z8[j] = keep + __shfl_xor(send, 16, 32);
    }
    bsel = (l >> 3) & 1;
    float z4v[4];
#pragma unroll
    for (int j = 0; j < 4; ++j) {
        float send = bsel ? z8[j] : z8[j + 4];
        float keep = bsel ? z8[j + 4] : z8[j];
        z4v[j] = keep + __shfl_xor(send, 8, 32);
    }
    bsel = (l >> 2) & 1;
    float z2v[2];
#pragma unroll
    for (int j = 0; j < 2; ++j) {
        float send = bsel ? z4v[j] : z4v[j + 2];
        float keep = bsel ? z4v[j + 2] : z4v[j];
        z2v[j] = keep + __shfl_xor(send, 4, 32);
    }
    bsel = (l >> 1) & 1;
    float z1v;
    {
        float send = bsel ? z2v[0] : z2v[1];
        float keep = bsel ? z2v[1] : z2v[0];
        z1v = keep + __shfl_xor(send, 2, 32);
    }
    z1v += __shfl_xor(z1v, 1, 32);
    if (!(l & 1)) zout[(long)n * NCLS + ((l >> 1) & 15)] = z1v;
}

// ---------------------------------------------------------------------------
// Layer 2 FUSED gather+softmax + bias + log_softmax, v2: two-phase per
// 32-edge chunk — each edge's score computed ONCE (1 exp/edge vs 16) by
// striding lanes, staged in LDS; all 16 lanes then gather z with broadcast
// LDS reads. Same-wave ordering -> barrier-free. 16 nodes per 256-block.
// ---------------------------------------------------------------------------
#define CH2 32   // edges per LDS chunk (fgather2)

__global__ __launch_bounds__(256)
void fgather2(const int* __restrict__ eoffs, const int* __restrict__ csr,
              const float* __restrict__ as2, const float* __restrict__ ad2,
              const float* __restrict__ z, const float* __restrict__ b2,
              float* __restrict__ out, int N) {
    __shared__ float wbuf[16][CH2];   // 2 KB
    __shared__ int   sbuf[16][CH2];   // 2 KB
    int g = threadIdx.x >> 4;
    int l = threadIdx.x & 15;
    int n = blockIdx.x * 16 + g;
    if (n >= N) return;
    int s0 = eoffs[n], s1 = eoffs[n + 1];
    float adn = ad2[n];
    float vs = as2[n] + adn; vs = (vs >= 0.f) ? vs : NEG_SLOPE * vs;

    float ps = __expf(vs);
    float acc = ps * z[(long)n * NCLS + l];
    float denp = 0.f;

    for (int base = s0; base < s1; base += CH2) {
        int cnt = min(CH2, s1 - base);
        // Phase A: score each edge once (lane-strided), stage w + src.
        for (int j = l; j < cnt; j += 16) {
            int s = csr[base + j];
            sbuf[g][j] = s;
            float v = as2[s] + adn; v = (v >= 0.f) ? v : NEG_SLOPE * v;
            float w = __expf(v);
            wbuf[g][j] = w;
            denp += w;
        }
        // Phase B: gather z (broadcast LDS reads of w/s).
        int j = 0;
        for (; j + 4 <= cnt; j += 4) {
            int sa = sbuf[g][j],     sb = sbuf[g][j + 1];
            int sc = sbuf[g][j + 2], sd = sbuf[g][j + 3];
            float wa = wbuf[g][j],     wb = wbuf[g][j + 1];
            float wc = wbuf[g][j + 2], wd = wbuf[g][j + 3];
            float za = z[sa * NCLS + l];
            float zb = z[sb * NCLS + l];
            float zc = z[sc * NCLS + l];
            float zd = z[sd * NCLS + l];
            acc = fmaf(za, wa, acc);
            acc = fmaf(zb, wb, acc);
            acc = fmaf(zc, wc, acc);
            acc = fmaf(zd, wd, acc);
        }
        for (; j < cnt; ++j) {
            acc = fmaf(z[sbuf[g][j] * NCLS + l], wbuf[g][j], acc);
        }
    }

    // Reduce partial denominators across the 16 lanes; add self.
    float den = denp;
#pragma unroll
    for (int off = 8; off >= 1; off >>= 1) den += __shfl_xor(den, off, 16);
    den += ps;

    float o = acc / (den + 1e-16f) + b2[l];

    float mx = o;
#pragma unroll
    for (int off = 8; off >= 1; off >>= 1) mx = fmaxf(mx, __shfl_xor(mx, off, 16));
    float ex = __expf(o - mx);
    float sum = ex;
#pragma unroll
    for (int off = 8; off >= 1; off >>= 1) sum += __shfl_xor(sum, off, 16);
    out[(long)n * NCLS + l] = o - mx - __logf(sum);
}

// ---------------------------------------------------------------------------
extern "C" void kernel_launch(void* const* d_in, const int* in_sizes, int n_in,
                              void* d_out, int out_size, void* d_ws, size_t ws_size,
                              hipStream_t stream) {
    const float* x        = (const float*)d_in[0];
    const int*   ei       = (const int*)  d_in[1];
    // d_in[2] = edge_attr (unused by reference)
    const float* W1       = (const float*)d_in[3];
    const float* att_src1 = (const float*)d_in[4];
    const float* att_dst1 = (const float*)d_in[5];
    const float* b1       = (const float*)d_in[6];
    const float* W2       = (const float*)d_in[7];
    const float* att_src2 = (const float*)d_in[8];
    const float* att_dst2 = (const float*)d_in[9];
    const float* b2       = (const float*)d_in[10];
    float* out = (float*)d_out;

    const int N = in_sizes[0] / FIN;        // 50000
    const int E = in_sizes[1] / 2;          // 800000
    const int NB = (N + 255) >> 8;          // 196 buckets
    const int EB = (E + EPB - 1) / EPB;     // 196 edge blocks (<=256)
    const int GB = (N + 63) / 64;           // 782 gemm1 blocks

    // gemm1 block slices fused into the 4 parallel CSR kernels
    int q = GB / 4, rr = GB % 4;
    int g0 = q + (rr > 0 ? 1 : 0);
    int g1 = q + (rr > 1 ? 1 : 0);
    int g2 = q + (rr > 2 ? 1 : 0);
    int g3 = q;
    int b0 = 0, b1o = g0, b2o = g0 + g1, b3o = g0 + g1 + g2;

    // Workspace layout (bytes)
    char* ws = (char*)d_ws;
    size_t off = 0;
    auto alloc = [&](size_t bytes) { char* p = ws + off; off += (bytes + 255) & ~(size_t)255; return p; };
    int*    blockhist     = (int*)  alloc((size_t)EB * NB * 4);
    int*    colsum        = (int*)  alloc((size_t)NB * 4);
    int*    bucket_base   = (int*)  alloc((size_t)(NB + 1) * 4);
    int*    tmp           = (int*)  alloc((size_t)E * 4);    // packed (src<<8)|dst&255
    int*    csr           = (int*)  alloc((size_t)E * 4);
    int*    eoffs         = (int*)  alloc((size_t)(N + 1) * 4);
    unsigned char* h1q    = (unsigned char*)alloc((size_t)N * HC1);  // fp8 e4m3
    float*  z             = (float*) alloc((size_t)N * NCLS * 4);
    float*  as1           = (float*) alloc((size_t)N * 2 * 4);
    float*  ad1           = (float*) alloc((size_t)N * 2 * 4);
    float*  as2           = (float*) alloc((size_t)N * 4);
    float*  ad2           = (float*) alloc((size_t)N * 4);
    float*  w2T           = (float*) alloc((size_t)NCLS * FIN * 4);
    float*  w2s           = (float*) alloc((size_t)FIN * 4);
    float*  w2d           = (float*) alloc((size_t)FIN * 4);
    (void)ws_size;

    f_bcnt<<<EB + g0, 256, 0, stream>>>(ei, blockhist, E, NB,
        x, W1, att_src1, att_dst1, h1q, as1, ad1, N, EB, b0);
    f_colscan<<<NB + g1, 256, 0, stream>>>(blockhist, colsum, EB, NB,
        x, W1, att_src1, att_dst1, h1q, as1, ad1, N, NB, b1o);
    bscan2_kernel<<<1, 256, 0, stream>>>(colsum, bucket_base, NB,
                                         W2, att_src2, att_dst2, w2T, w2s, w2d);
    f_binA<<<EB + g2, 256, 0, stream>>>(ei, blockhist, bucket_base, tmp, E, NB,
        x, W1, att_src1, att_dst1, h1q, as1, ad1, N, EB, b2o);
    f_binB<<<NB + g3, 256, 0, stream>>>(tmp, bucket_base, csr, eoffs, E, N,
        x, W1, att_src1, att_dst1, h1q, as1, ad1, NB, b3o);

    fgather1<<<(N + 7) / 8, 256, 0, stream>>>(
        eoffs, csr, as1, ad1, h1q, b1, w2T, w2s, w2d, z, as2, ad2, N);
    fgather2<<<(N + 15) / 16, 256, 0, stream>>>(eoffs, csr, as2, ad2, z, b2, out, N);
}

// Round 21
// 94.042 us; speedup vs baseline: 1.1972x; 1.0195x over previous
//
#include <hip/hip_runtime.h>
#include <math.h>

// Problem constants (match reference)
#define FIN   128
#define HC1   128   // H*C for layer 1
#define NCLS  16
#define NEG_SLOPE 0.2f

typedef __attribute__((ext_vector_type(8))) short bf16x8;
typedef __attribute__((ext_vector_type(4))) float f32x4;
typedef __attribute__((ext_vector_type(2))) float f32x2;

__device__ __forceinline__ unsigned short f2bf_rne(float f) {
    unsigned int u = __float_as_uint(f);
    unsigned int r = u + 0x7FFFu + ((u >> 16) & 1u);
    return (unsigned short)(r >> 16);
}
__device__ __forceinline__ float bf2f(unsigned short h) {
    return __uint_as_float(((unsigned int)h) << 16);
}

// fp8 e4m3 encode via HW converter (round-trips with the decode below).
__device__ __forceinline__ unsigned char f2fp8(float v) {
    int p = __builtin_amdgcn_cvt_pk_fp8_f32(v, v, 0, false);
    return (unsigned char)(p & 0xFF);
}

#define EPB 4096   // edges per block in bcnt/binA  (EB = ceil(E/EPB) must be <=256)

// ---------------------------------------------------------------------------
// gemm1 body, single-bf16 MFMA (h1 is fp8 anyway; bf16 error 0.4% << fp8 3.6%):
// h1 = x@W1 -> fp8 e4m3 + fused alpha1 reductions. 32 MFMA/block, 32 KB LDS.
// ---------------------------------------------------------------------------
__device__ __forceinline__
void gemm1_body(const float* __restrict__ x, const float* __restrict__ W,
                const float* __restrict__ a_src, const float* __restrict__ a_dst,
                unsigned char* __restrict__ h1q, float* __restrict__ as1,
                float* __restrict__ ad1, int N, int bid, float4* smem) {
    unsigned short* whi = (unsigned short*)smem;          // 32 KB, fragment-ordered
    int tid = threadIdx.x;

#pragma unroll
    for (int i = 0; i < 64; ++i) {
        int idx = tid + i * 256;            // 0..16383, coalesced
        int k = idx >> 7, c = idx & 127;
        float v = W[idx];
        unsigned short hb = f2bf_rne(v);
        int kb = k >> 5, kk = k & 31;
        int g = kk >> 3, j = kk & 7;
        int ct = c >> 4, li = c & 15;
        int off = ((kb * 8 + ct) * 64 + g * 16 + li) * 8 + j;
        whi[off] = hb;
    }

    int wid = tid >> 6, lane = tid & 63;
    int li = lane & 15, g = lane >> 4;
    int rowbase = bid * 64 + wid * 16;

    int arow = rowbase + li;
    if (arow >= N) arow = N - 1;            // clamp; invalid rows never stored
    const float* xp = x + (long)arow * FIN + g * 8;
    bf16x8 Ahi[4];
#pragma unroll
    for (int kb = 0; kb < 4; ++kb) {
        float4 v0 = *reinterpret_cast<const float4*>(xp + kb * 32);
        float4 v1 = *reinterpret_cast<const float4*>(xp + kb * 32 + 4);
        bf16x8 h8;
        h8[0] = (short)f2bf_rne(v0.x); h8[1] = (short)f2bf_rne(v0.y);
        h8[2] = (short)f2bf_rne(v0.z); h8[3] = (short)f2bf_rne(v0.w);
        h8[4] = (short)f2bf_rne(v1.x); h8[5] = (short)f2bf_rne(v1.y);
        h8[6] = (short)f2bf_rne(v1.z); h8[7] = (short)f2bf_rne(v1.w);
        Ahi[kb] = h8;
    }

    float asr[8], adr[8];
#pragma unroll
    for (int ct = 0; ct < 8; ++ct) {
        asr[ct] = a_src[ct * 16 + li];
        adr[ct] = a_dst[ct * 16 + li];
    }

    __syncthreads();

    f32x4 acc[8];
#pragma unroll
    for (int ct = 0; ct < 8; ++ct) acc[ct] = (f32x4){0.f, 0.f, 0.f, 0.f};

#pragma unroll
    for (int kb = 0; kb < 4; ++kb) {
#pragma unroll
        for (int ct = 0; ct < 8; ++ct) {
            bf16x8 bh = *reinterpret_cast<const bf16x8*>(&whi[((kb * 8 + ct) * 64 + lane) * 8]);
            acc[ct] = __builtin_amdgcn_mfma_f32_16x16x32_bf16(Ahi[kb], bh, acc[ct], 0, 0, 0);
        }
    }

#pragma unroll
    for (int q = 0; q < 4; ++q) {
        int n = rowbase + g * 4 + q;
        bool valid = (n < N);
        float p0s = 0.f, p1s = 0.f, p0d = 0.f, p1d = 0.f;
#pragma unroll
        for (int ct = 0; ct < 8; ++ct) {
            float h = acc[ct][q];
            if (valid) h1q[(long)n * HC1 + ct * 16 + li] = f2fp8(h);
            if (ct < 4) { p0s = fmaf(h, asr[ct], p0s); p0d = fmaf(h, adr[ct], p0d); }
            else        { p1s = fmaf(h, asr[ct], p1s); p1d = fmaf(h, adr[ct], p1d); }
        }
#pragma unroll
        for (int off = 8; off >= 1; off >>= 1) {
            p0s += __shfl_xor(p0s, off, 16);
            p1s += __shfl_xor(p1s, off, 16);
            p0d += __shfl_xor(p0d, off, 16);
            p1d += __shfl_xor(p1d, off, 16);
        }
        if (valid && li == 0) {
            as1[n * 2 + 0] = p0s; as1[n * 2 + 1] = p1s;
            ad1[n * 2 + 0] = p0d; ad1[n * 2 + 1] = p1d;
        }
    }
}

// ---------------------------------------------------------------------------
// FUSED CSR-build kernels: first nb_csr blocks do the CSR phase, remaining
// blocks run a gemm1 slice. tmp packed: (src<<8)|(dst&255), src < 2^24.
// ---------------------------------------------------------------------------
__global__ __launch_bounds__(256)
void f_bcnt(const int* __restrict__ ei, int* __restrict__ blockhist, int E, int NB,
            const float* __restrict__ x, const float* __restrict__ W1,
            const float* __restrict__ a_src, const float* __restrict__ a_dst,
            unsigned char* __restrict__ h1q, float* __restrict__ as1,
            float* __restrict__ ad1, int N, int nb_csr, int gemm_base) {
    __shared__ float4 smem[2048];   // 32 KB shared scratch
    int tid = threadIdx.x;
    if ((int)blockIdx.x >= nb_csr) {
        gemm1_body(x, W1, a_src, a_dst, h1q, as1, ad1, N,
                   gemm_base + blockIdx.x - nb_csr, smem);
        return;
    }
    int* h = (int*)smem;
    h[tid] = 0;
    __syncthreads();
    int base = blockIdx.x * EPB;
#pragma unroll
    for (int j = 0; j < EPB / 256; ++j) {
        int e = base + j * 256 + tid;
        if (e < E) atomicAdd(&h[ei[E + e] >> 8], 1);
    }
    __syncthreads();
    if (tid < NB) blockhist[blockIdx.x * NB + tid] = h[tid];
}

__global__ __launch_bounds__(256)
void f_colscan(int* __restrict__ blockhist, int* __restrict__ colsum, int EB, int NB,
               const float* __restrict__ x, const float* __restrict__ W1,
               const float* __restrict__ a_src, const float* __restrict__ a_dst,
               unsigned char* __restrict__ h1q, float* __restrict__ as1,
               float* __restrict__ ad1, int N, int nb_csr, int gemm_base) {
    __shared__ float4 smem[2048];
    int b = threadIdx.x;
    if ((int)blockIdx.x >= nb_csr) {
        gemm1_body(x, W1, a_src, a_dst, h1q, as1, ad1, N,
                   gemm_base + blockIdx.x - nb_csr, smem);
        return;
    }
    int* lds = (int*)smem;
    int t = blockIdx.x;       // bucket (column)
    int v = (b < EB) ? blockhist[b * NB + t] : 0;
    lds[b] = v;
    __syncthreads();
    for (int off = 1; off < 256; off <<= 1) {
        int u = (b >= off) ? lds[b - off] : 0;
        __syncthreads();
        lds[b] += u;
        __syncthreads();
    }
    if (b < EB) blockhist[b * NB + t] = lds[b] - v;   // excl offset within bucket
    if (b == 255) colsum[t] = lds[255];
}

// 1 block: exclusive scan of colsum -> bucket_base; + W2 prep.
__global__ __launch_bounds__(256)
void bscan2_kernel(const int* __restrict__ colsum, int* __restrict__ bucket_base,
                   int NB, const float* __restrict__ W2,
                   const float* __restrict__ a_src2, const float* __restrict__ a_dst2,
                   float* __restrict__ w2T, float* __restrict__ w2s,
                   float* __restrict__ w2d) {
    __shared__ int lds[256];
    int t = threadIdx.x;
    int v = (t < NB) ? colsum[t] : 0;
    lds[t] = v;
    __syncthreads();
    for (int off = 1; off < 256; off <<= 1) {
        int u = (t >= off) ? lds[t - off] : 0;
        __syncthreads();
        lds[t] += u;
        __syncthreads();
    }
    if (t < NB) bucket_base[t] = lds[t] - v;
    if (t == 255) bucket_base[NB] = lds[255];   // == E

    if (t < FIN) {
        float s = 0.f, d = 0.f;
#pragma unroll
        for (int c = 0; c < NCLS; ++c) {
            float w = W2[t * NCLS + c];
            w2T[c * FIN + t] = w;
            s = fmaf(w, a_src2[c], s);
            d = fmaf(w, a_dst2[c], d);
        }
        w2s[t] = s; w2d[t] = d;
    }
}

__global__ __launch_bounds__(256)
void f_binA(const int* __restrict__ ei, const int* __restrict__ blockhist,
            const int* __restrict__ bucket_base, int* __restrict__ tmp,
            int E, int NB,
            const float* __restrict__ x, const float* __restrict__ W1,
            const float* __restrict__ a_src, const float* __restrict__ a_dst,
            unsigned char* __restrict__ h1q, float* __restrict__ as1,
            float* __restrict__ ad1, int N, int nb_csr, int gemm_base) {
    __shared__ float4 smem[2048];
    int tid = threadIdx.x;
    if ((int)blockIdx.x >= nb_csr) {
        gemm1_body(x, W1, a_src, a_dst, h1q, as1, ad1, N,
                   gemm_base + blockIdx.x - nb_csr, smem);
        return;
    }
    int* h  = (int*)smem;        // local cursors [256]
    int* bb = h + 256;           // global base per bucket [256]
    h[tid] = 0;
    if (tid < NB) bb[tid] = blockhist[blockIdx.x * NB + tid] + bucket_base[tid];
    __syncthreads();
    int base = blockIdx.x * EPB;
#pragma unroll
    for (int j = 0; j < EPB / 256; ++j) {
        int e = base + j * 256 + tid;
        if (e < E) {
            int s = ei[e], d = ei[E + e];
            int b = d >> 8;
            int r = atomicAdd(&h[b], 1);
            tmp[bb[b] + r] = (s << 8) | (d & 255);   // packed
        }
    }
}

__global__ __launch_bounds__(256)
void f_binB(const int* __restrict__ tmp, const int* __restrict__ bucket_base,
            int* __restrict__ csr, int* __restrict__ eoffs, int E, int N,
            const float* __restrict__ x, const float* __restrict__ W1,
            const float* __restrict__ a_src, const float* __restrict__ a_dst,
            unsigned char* __restrict__ h1q, float* __restrict__ as1,
            float* __restrict__ ad1, int nb_csr, int gemm_base) {
    __shared__ float4 smem[2048];
    int t = threadIdx.x;
    if ((int)blockIdx.x >= nb_csr) {
        gemm1_body(x, W1, a_src, a_dst, h1q, as1, ad1, N,
                   gemm_base + blockIdx.x - nb_csr, smem);
        return;
    }
    int* cnt = (int*)smem;       // [256]
    int* lds = cnt + 256;        // [256]
    int* cur = cnt + 512;        // [256]
    int b = blockIdx.x;
    int lo = bucket_base[b], hi = bucket_base[b + 1];
    cnt[t] = 0;
    __syncthreads();
    for (int i = lo + t; i < hi; i += 256)
        atomicAdd(&cnt[tmp[i] & 255], 1);
    __syncthreads();
    int v = cnt[t];
    lds[t] = v;
    __syncthreads();
    for (int off = 1; off < 256; off <<= 1) {
        int u = (t >= off) ? lds[t - off] : 0;
        __syncthreads();
        lds[t] += u;
        __syncthreads();
    }
    int excl = lds[t] - v;
    int node = b * 256 + t;
    if (node < N) eoffs[node] = lo + excl;
    if (b == 0 && t == 0) eoffs[N] = E;
    cur[t] = lo + excl;
    __syncthreads();
    for (int i = lo + t; i < hi; i += 256) {
        int e = tmp[i];
        int p = atomicAdd(&cur[e & 255], 1);
        csr[p] = ((unsigned int)e) >> 8;     // src
    }
}

// ---------------------------------------------------------------------------
// Layer 1 FUSED gather+softmax+ELU+GEMM2+alpha2 over fp8 h1 rows:
// two-phase per 64-edge chunk (score dedup via LDS). Unchanged from R19.
// ---------------------------------------------------------------------------
#define CH 64   // edges per LDS chunk (fgather1)

__global__ __launch_bounds__(256)
void fgather1(const int* __restrict__ eoffs, const int* __restrict__ csr,
              const float* __restrict__ as_arr, const float* __restrict__ ad_arr,
              const unsigned char* __restrict__ h1q, const float* __restrict__ b1,
              const float* __restrict__ w2T, const float* __restrict__ w2s,
              const float* __restrict__ w2d,
              float* __restrict__ zout, float* __restrict__ as2,
              float* __restrict__ ad2, int N) {
    __shared__ float wbuf[8][2][CH];   // [group][head][edge]  4 KB
    __shared__ int   sbuf[8][CH];      // 2 KB
    int tid = threadIdx.x;
    int g = tid >> 5;                // 0..7 node-group in block (32-lane aligned)
    int l = tid & 31;                // lane in group: cols 4l..4l+3
    int n = blockIdx.x * 8 + g;
    if (n >= N) return;
    int head = l >> 4;
    int hl = l & 15;                 // lane within head-group
    int s0 = eoffs[n], s1 = eoffs[n + 1];

    float ad0 = ad_arr[2 * n], ad1v = ad_arr[2 * n + 1];
    float2 aself = *reinterpret_cast<const float2*>(&as_arr[2 * n]);
    float vs0 = aself.x + ad0;  vs0 = (vs0 >= 0.f) ? vs0 : NEG_SLOPE * vs0;
    float vs1 = aself.y + ad1v; vs1 = (vs1 >= 0.f) ? vs1 : NEG_SLOPE * vs1;
    float adn = head ? ad1v : ad0;

    float ps = __expf(head ? vs1 : vs0);
    unsigned int us = *reinterpret_cast<const unsigned int*>(&h1q[((long)n << 7) + 4 * l]);
    f32x2 slo = __builtin_amdgcn_cvt_pk_f32_fp8(us, false);
    f32x2 shi = __builtin_amdgcn_cvt_pk_f32_fp8(us, true);
    float4 acc;
    acc.x = slo[0] * ps; acc.y = slo[1] * ps;
    acc.z = shi[0] * ps; acc.w = shi[1] * ps;
    float denp = 0.f;   // per-lane partial denominator (reduced at end)

    for (int base = s0; base < s1; base += CH) {
        int cnt = min(CH, s1 - base);
        // Phase A: score each edge once per head; stage w and src in LDS.
        for (int j = hl; j < cnt; j += 16) {
            int s = csr[base + j];
            if (head == 0) sbuf[g][j] = s;
            float av = as_arr[2 * s + head];
            float v = av + adn; v = (v >= 0.f) ? v : NEG_SLOPE * v;
            float w = __expf(v);
            wbuf[g][head][j] = w;
            denp += w;
        }
        // Phase B: gather (broadcast LDS reads of w/s).
        int j = 0;
        for (; j + 4 <= cnt; j += 4) {
            int sa = sbuf[g][j],     sb = sbuf[g][j + 1];
            int sc = sbuf[g][j + 2], sd = sbuf[g][j + 3];
            float wa = wbuf[g][head][j],     wb = wbuf[g][head][j + 1];
            float wc = wbuf[g][head][j + 2], wd = wbuf[g][head][j + 3];
            unsigned int ua = *reinterpret_cast<const unsigned int*>(&h1q[((long)sa << 7) + 4 * l]);
            unsigned int ub = *reinterpret_cast<const unsigned int*>(&h1q[((long)sb << 7) + 4 * l]);
            unsigned int uc = *reinterpret_cast<const unsigned int*>(&h1q[((long)sc << 7) + 4 * l]);
            unsigned int ud = *reinterpret_cast<const unsigned int*>(&h1q[((long)sd << 7) + 4 * l]);
            f32x2 lo, hi;
            lo = __builtin_amdgcn_cvt_pk_f32_fp8(ua, false);
            hi = __builtin_amdgcn_cvt_pk_f32_fp8(ua, true);
            acc.x = fmaf(lo[0], wa, acc.x); acc.y = fmaf(lo[1], wa, acc.y);
            acc.z = fmaf(hi[0], wa, acc.z); acc.w = fmaf(hi[1], wa, acc.w);
            lo = __builtin_amdgcn_cvt_pk_f32_fp8(ub, false);
            hi = __builtin_amdgcn_cvt_pk_f32_fp8(ub, true);
            acc.x = fmaf(lo[0], wb, acc.x); acc.y = fmaf(lo[1], wb, acc.y);
            acc.z = fmaf(hi[0], wb, acc.z); acc.w = fmaf(hi[1], wb, acc.w);
            lo = __builtin_amdgcn_cvt_pk_f32_fp8(uc, false);
            hi = __builtin_amdgcn_cvt_pk_f32_fp8(uc, true);
            acc.x = fmaf(lo[0], wc, acc.x); acc.y = fmaf(lo[1], wc, acc.y);
            acc.z = fmaf(hi[0], wc, acc.z); acc.w = fmaf(hi[1], wc, acc.w);
            lo = __builtin_amdgcn_cvt_pk_f32_fp8(ud, false);
            hi = __builtin_amdgcn_cvt_pk_f32_fp8(ud, true);
            acc.x = fmaf(lo[0], wd, acc.x); acc.y = fmaf(lo[1], wd, acc.y);
            acc.z = fmaf(hi[0], wd, acc.z); acc.w = fmaf(hi[1], wd, acc.w);
        }
        for (; j < cnt; ++j) {
            int s = sbuf[g][j];
            float w = wbuf[g][head][j];
            unsigned int u = *reinterpret_cast<const unsigned int*>(&h1q[((long)s << 7) + 4 * l]);
            f32x2 lo = __builtin_amdgcn_cvt_pk_f32_fp8(u, false);
            f32x2 hi = __builtin_amdgcn_cvt_pk_f32_fp8(u, true);
            acc.x = fmaf(lo[0], w, acc.x); acc.y = fmaf(lo[1], w, acc.y);
            acc.z = fmaf(hi[0], w, acc.z); acc.w = fmaf(hi[1], w, acc.w);
        }
    }

    // Reduce partial denominators within each 16-lane head group; add self.
    float den = denp;
#pragma unroll
    for (int off = 8; off >= 1; off >>= 1) den += __shfl_xor(den, off, 16);
    den += ps;

    float r = 1.f / (den + 1e-16f);
    int col = 4 * l;
    float4 bb = *reinterpret_cast<const float4*>(&b1[col]);
    float4 o;
    o.x = acc.x * r + bb.x; o.y = acc.y * r + bb.y;
    o.z = acc.z * r + bb.z; o.w = acc.w * r + bb.w;
    o.x = (o.x > 0.f) ? o.x : expm1f(o.x);
    o.y = (o.y > 0.f) ? o.y : expm1f(o.y);
    o.z = (o.z > 0.f) ? o.z : expm1f(o.z);
    o.w = (o.w > 0.f) ? o.w : expm1f(o.w);

    // as2/ad2 = h2 . (W2 @ a_src2), h2 . (W2 @ a_dst2)  -- 10 shfl
    float4 ws4 = *reinterpret_cast<const float4*>(&w2s[col]);
    float4 wd4 = *reinterpret_cast<const float4*>(&w2d[col]);
    float sa2 = o.x * ws4.x + o.y * ws4.y + o.z * ws4.z + o.w * ws4.w;
    float da2 = o.x * wd4.x + o.y * wd4.y + o.z * wd4.z + o.w * wd4.w;
#pragma unroll
    for (int off = 16; off >= 1; off >>= 1) {
        sa2 += __shfl_xor(sa2, off, 32);
        da2 += __shfl_xor(da2, off, 32);
    }
    if (l == 0) { as2[n] = sa2; ad2[n] = da2; }

    // z = h2 @ W2 via class-fold butterfly (16 shfl total).
    float zp[NCLS];
#pragma unroll
    for (int c = 0; c < NCLS; ++c) {
        float4 w4 = *reinterpret_cast<const float4*>(&w2T[c * FIN + col]);
        zp[c] = o.x * w4.x + o.y * w4.y + o.z * w4.z + o.w * w4.w;
    }
    int bsel = (l >> 4) & 1;
    float z8[8];
#pragma unroll
    for (int j = 0; j < 8; ++j) {
        float send = bsel ? zp[j] : zp[j + 8];
        float keep = bsel ? zp[j + 8] : zp[j];
        z8[j] = keep + __shfl_xor(send, 16, 32);
    }
    bsel = (l >> 3) & 1;
    float z4v[4];
#pragma unroll
    for (int j = 0; j < 4; ++j) {
        float send = bsel ? z8[j] : z8[j + 4];
        float keep = bsel ? z8[j + 4] : z8[j];
        z4v[j] = keep + __shfl_xor(send, 8, 32);
    }
    bsel = (l >> 2) & 1;
    float z2v[2];
#pragma unroll
    for (int j = 0; j < 2; ++j) {
        float send = bsel ? z4v[j] : z4v[j + 2];
        float keep = bsel ? z4v[j + 2] : z4v[j];
        z2v[j] = keep + __shfl_xor(send, 4, 32);
    }
    bsel = (l >> 1) & 1;
    float z1v;
    {
        float send = bsel ? z2v[0] : z2v[1];
        float keep = bsel ? z2v[1] : z2v[0];
        z1v = keep + __shfl_xor(send, 2, 32);
    }
    z1v += __shfl_xor(z1v, 1, 32);
    if (!(l & 1)) zout[(long)n * NCLS + ((l >> 1) & 15)] = z1v;
}

// ---------------------------------------------------------------------------
// Layer 2 FUSED gather+softmax + bias + log_softmax, two-phase score dedup.
// Unchanged from R20.
// ---------------------------------------------------------------------------
#define CH2 32   // edges per LDS chunk (fgather2)

__global__ __launch_bounds__(256)
void fgather2(const int* __restrict__ eoffs, const int* __restrict__ csr,
              const float* __restrict__ as2, const float* __restrict__ ad2,
              const float* __restrict__ z, const float* __restrict__ b2,
              float* __restrict__ out, int N) {
    __shared__ float wbuf[16][CH2];   // 2 KB
    __shared__ int   sbuf[16][CH2];   // 2 KB
    int g = threadIdx.x >> 4;
    int l = threadIdx.x & 15;
    int n = blockIdx.x * 16 + g;
    if (n >= N) return;
    int s0 = eoffs[n], s1 = eoffs[n + 1];
    float adn = ad2[n];
    float vs = as2[n] + adn; vs = (vs >= 0.f) ? vs : NEG_SLOPE * vs;

    float ps = __expf(vs);
    float acc = ps * z[(long)n * NCLS + l];
    float denp = 0.f;

    for (int base = s0; base < s1; base += CH2) {
        int cnt = min(CH2, s1 - base);
        // Phase A: score each edge once (lane-strided), stage w + src.
        for (int j = l; j < cnt; j += 16) {
            int s = csr[base + j];
            sbuf[g][j] = s;
            float v = as2[s] + adn; v = (v >= 0.f) ? v : NEG_SLOPE * v;
            float w = __expf(v);
            wbuf[g][j] = w;
            denp += w;
        }
        // Phase B: gather z (broadcast LDS reads of w/s).
        int j = 0;
        for (; j + 4 <= cnt; j += 4) {
            int sa = sbuf[g][j],     sb = sbuf[g][j + 1];
            int sc = sbuf[g][j + 2], sd = sbuf[g][j + 3];
            float wa = wbuf[g][j],     wb = wbuf[g][j + 1];
            float wc = wbuf[g][j + 2], wd = wbuf[g][j + 3];
            float za = z[sa * NCLS + l];
            float zb = z[sb * NCLS + l];
            float zc = z[sc * NCLS + l];
            float zd = z[sd * NCLS + l];
            acc = fmaf(za, wa, acc);
            acc = fmaf(zb, wb, acc);
            acc = fmaf(zc, wc, acc);
            acc = fmaf(zd, wd, acc);
        }
        for (; j < cnt; ++j) {
            acc = fmaf(z[sbuf[g][j] * NCLS + l], wbuf[g][j], acc);
        }
    }

    // Reduce partial denominators across the 16 lanes; add self.
    float den = denp;
#pragma unroll
    for (int off = 8; off >= 1; off >>= 1) den += __shfl_xor(den, off, 16);
    den += ps;

    float o = acc / (den + 1e-16f) + b2[l];

    float mx = o;
#pragma unroll
    for (int off = 8; off >= 1; off >>= 1) mx = fmaxf(mx, __shfl_xor(mx, off, 16));
    float ex = __expf(o - mx);
    float sum = ex;
#pragma unroll
    for (int off = 8; off >= 1; off >>= 1) sum += __shfl_xor(sum, off, 16);
    out[(long)n * NCLS + l] = o - mx - __logf(sum);
}

// ---------------------------------------------------------------------------
extern "C" void kernel_launch(void* const* d_in, const int* in_sizes, int n_in,
                              void* d_out, int out_size, void* d_ws, size_t ws_size,
                              hipStream_t stream) {
    const float* x        = (const float*)d_in[0];
    const int*   ei       = (const int*)  d_in[1];
    // d_in[2] = edge_attr (unused by reference)
    const float* W1       = (const float*)d_in[3];
    const float* att_src1 = (const float*)d_in[4];
    const float* att_dst1 = (const float*)d_in[5];
    const float* b1       = (const float*)d_in[6];
    const float* W2       = (const float*)d_in[7];
    const float* att_src2 = (const float*)d_in[8];
    const float* att_dst2 = (const float*)d_in[9];
    const float* b2       = (const float*)d_in[10];
    float* out = (float*)d_out;

    const int N = in_sizes[0] / FIN;        // 50000
    const int E = in_sizes[1] / 2;          // 800000
    const int NB = (N + 255) >> 8;          // 196 buckets
    const int EB = (E + EPB - 1) / EPB;     // 196 edge blocks (<=256)
    const int GB = (N + 63) / 64;           // 782 gemm1 blocks

    // gemm1 block slices fused into the 4 parallel CSR kernels
    int q = GB / 4, rr = GB % 4;
    int g0 = q + (rr > 0 ? 1 : 0);
    int g1 = q + (rr > 1 ? 1 : 0);
    int g2 = q + (rr > 2 ? 1 : 0);
    int g3 = q;
    int b0 = 0, b1o = g0, b2o = g0 + g1, b3o = g0 + g1 + g2;

    // Workspace layout (bytes)
    char* ws = (char*)d_ws;
    size_t off = 0;
    auto alloc = [&](size_t bytes) { char* p = ws + off; off += (bytes + 255) & ~(size_t)255; return p; };
    int*    blockhist     = (int*)  alloc((size_t)EB * NB * 4);
    int*    colsum        = (int*)  alloc((size_t)NB * 4);
    int*    bucket_base   = (int*)  alloc((size_t)(NB + 1) * 4);
    int*    tmp           = (int*)  alloc((size_t)E * 4);    // packed (src<<8)|dst&255
    int*    csr           = (int*)  alloc((size_t)E * 4);
    int*    eoffs         = (int*)  alloc((size_t)(N + 1) * 4);
    unsigned char* h1q    = (unsigned char*)alloc((size_t)N * HC1);  // fp8 e4m3
    float*  z             = (float*) alloc((size_t)N * NCLS * 4);
    float*  as1           = (float*) alloc((size_t)N * 2 * 4);
    float*  ad1           = (float*) alloc((size_t)N * 2 * 4);
    float*  as2           = (float*) alloc((size_t)N * 4);
    float*  ad2           = (float*) alloc((size_t)N * 4);
    float*  w2T           = (float*) alloc((size_t)NCLS * FIN * 4);
    float*  w2s           = (float*) alloc((size_t)FIN * 4);
    float*  w2d           = (float*) alloc((size_t)FIN * 4);
    (void)ws_size;

    f_bcnt<<<EB + g0, 256, 0, stream>>>(ei, blockhist, E, NB,
        x, W1, att_src1, att_dst1, h1q, as1, ad1, N, EB, b0);
    f_colscan<<<NB + g1, 256, 0, stream>>>(blockhist, colsum, EB, NB,
        x, W1, att_src1, att_dst1, h1q, as1, ad1, N, NB, b1o);
    bscan2_kernel<<<1, 256, 0, stream>>>(colsum, bucket_base, NB,
                                         W2, att_src2, att_dst2, w2T, w2s, w2d);
    f_binA<<<EB + g2, 256, 0, stream>>>(ei, blockhist, bucket_base, tmp, E, NB,
        x, W1, att_src1, att_dst1, h1q, as1, ad1, N, EB, b2o);
    f_binB<<<NB + g3, 256, 0, stream>>>(tmp, bucket_base, csr, eoffs, E, N,
        x, W1, att_src1, att_dst1, h1q, as1, ad1, NB, b3o);

    fgather1<<<(N + 7) / 8, 256, 0, stream>>>(
        eoffs, csr, as1, ad1, h1q, b1, w2T, w2s, w2d, z, as2, ad2, N);
    fgather2<<<(N + 15) / 16, 256, 0, stream>>>(eoffs, csr, as2, ad2, z, b2, out, N);
}